// Round 5
// baseline (226.948 us; speedup 1.0000x reference)
//
#include <hip/hip_runtime.h>
#include <hip/hip_bf16.h>

// ---- types ----
typedef __bf16 bf16_t;
typedef __bf16 bf16x2 __attribute__((ext_vector_type(2)));
typedef __bf16 bf16x4 __attribute__((ext_vector_type(4)));
typedef __bf16 bf16x8 __attribute__((ext_vector_type(8)));
typedef float  f32x4  __attribute__((ext_vector_type(4)));
typedef int    i32x2  __attribute__((ext_vector_type(2)));

#define D_MODEL 1024
#define HEADS   16
#define HD      64
#define BB      2
#define TT      2048
#define MROWS   (BB*TT)   // 4096

#define GLDS16(g, l) __builtin_amdgcn_global_load_lds( \
    (const __attribute__((address_space(1))) void*)(g), \
    (__attribute__((address_space(3))) void*)(l), 16, 0, 0)

static __device__ __forceinline__ int pack_bf16(float a, float b) {
    bf16x2 t; t[0] = (bf16_t)a; t[1] = (bf16_t)b;
    return __builtin_bit_cast(int, t);
}

// ---- R9 block table: 40 blocks/bh = unsplit qt 0..23 + split halves of qt 24..31.
// CU-set = (g, bh) with members r_=0..4 (stride-256 cyclic dispatch, 5 blocks/CU).
// Every set sums to 66 rounds; max block = 24 rounds (was 32).
__constant__ unsigned char TQT[8][5] = {
    {23, 22, 31,  1,  0},
    {21, 20, 31,  3,  2},
    {19, 18, 30,  5,  4},
    {17, 16, 15,  7,  6},
    {14, 28, 13, 12,  8},
    {29, 29, 27, 11,  9},
    {30, 27, 24, 25, 10},
    {28, 26, 25, 26, 24},
};
__constant__ unsigned char TK0[8][5] = {
    { 0,  0,  0,  0,  0},
    { 0,  0, 16,  0,  0},
    { 0,  0,  0,  0,  0},
    { 0,  0,  0,  0,  0},
    { 0,  0,  0,  0,  0},
    { 0, 15,  0,  0,  0},
    {16, 14,  0,  0,  0},
    {15,  0, 13, 14, 13},
};
__constant__ unsigned char TK1[8][5] = {
    {24, 23, 16,  2,  1},
    {22, 21, 32,  4,  3},
    {20, 19, 16,  6,  5},
    {18, 17, 16,  8,  7},
    {15, 15, 14, 13,  9},
    {15, 30, 14, 12, 10},
    {31, 28, 13, 13, 11},
    {29, 14, 26, 27, 25},
};

// ---------------- fused fp32 -> bf16 convert (+ zero split-merge counters) ----
__global__ __launch_bounds__(256) void cvt_all_kernel(const float* __restrict__ x,
                                                      const float* __restrict__ wq,
                                                      const float* __restrict__ wk,
                                                      const float* __restrict__ wv,
                                                      const float* __restrict__ wo,
                                                      bf16_t* __restrict__ dst,
                                                      unsigned int* __restrict__ cnt) {
    if (blockIdx.x == 0) cnt[threadIdx.x] = 0;      // 256 pair counters
    const int i = blockIdx.x * 256 + threadIdx.x;   // vec4 index, total 2097152
    const float* src;
    int s;
    if (i < 1048576) { src = x; s = i; }
    else {
        int j = i - 1048576;
        int w = j >> 18;          // 262144 vec4 per weight
        s = j & 262143;
        src = (w == 0) ? wq : (w == 1) ? wk : (w == 2) ? wv : wo;
    }
    float4 v = reinterpret_cast<const float4*>(src)[s];
    bf16x4 o;
    o[0] = (bf16_t)v.x; o[1] = (bf16_t)v.y; o[2] = (bf16_t)v.z; o[3] = (bf16_t)v.w;
    reinterpret_cast<bf16x4*>(dst)[i] = o;
}

// ---------------- bf16 GEMM: C[M,N] = A[M,K] * B[N,K]^T ----------------
// BN = 128 or 64 (N-tile). M-tile fixed 128.
// MODE 0: fused QKV scatter (N=3072) -> [B,H,T,D] each; Q at Cout+0 (pre-scaled
//         by 0.125*log2e in fp32 before bf16 rounding), K at +4M, V at +12M
//         elements (the Ow slot, later transposed to Vt).
// MODE 2: fp32 row-major [M,N] (final output)
template<int MODE, int BN>
__global__ __launch_bounds__(256) void gemm_bt(const bf16_t* __restrict__ A,
                                               const bf16_t* __restrict__ Bw,
                                               void* __restrict__ Cout,
                                               int M, int N, int K) {
    constexpr int NI = BN / 32;     // n-tiles of 16 per wave
    __shared__ __align__(16) bf16_t As[128*32];
    __shared__ __align__(16) bf16_t Bs[BN*32];
    const int tid   = threadIdx.x;
    const int lane  = tid & 63;
    const int wave  = tid >> 6;
    const int col16 = lane & 15;
    const int quad  = lane >> 4;
    const int wrow  = (wave & 1) * 64;
    const int wcol  = (wave >> 1) * (BN / 2);
    const int bm    = blockIdx.y * 128;
    const int bn    = blockIdx.x * BN;

    const int lr = tid >> 2;        // 0..63
    const int lc = (tid & 3) * 8;   // 0,8,16,24

    const bf16_t* agp = &A [(size_t)(bm + lr)*K + lc];
    const bf16_t* bgp = &Bw[(size_t)(bn + lr)*K + lc];
    const size_t half = (size_t)64 * K;
    bf16_t* as_lo = &As[wave*512];
    bf16_t* as_hi = &As[2048 + wave*512];
    bf16_t* bs_lo = &Bs[wave*512];
    bf16_t* bs_hi = &Bs[2048 + wave*512];   // only used when BN==128

    f32x4 acc[4][NI];
#pragma unroll
    for (int i = 0; i < 4; i++)
#pragma unroll
        for (int j = 0; j < NI; j++) acc[i][j] = (f32x4){0.f, 0.f, 0.f, 0.f};

    for (int k0 = 0; k0 < K; k0 += 32) {
        GLDS16(agp + k0,        as_lo);
        GLDS16(agp + half + k0, as_hi);
        GLDS16(bgp + k0,        bs_lo);
        if (BN == 128) GLDS16(bgp + half + k0, bs_hi);
        __syncthreads();

        bf16x8 af[4], bfr[NI];
#pragma unroll
        for (int mi = 0; mi < 4; mi++)
            af[mi] = *reinterpret_cast<const bf16x8*>(&As[(wrow + mi*16 + col16)*32 + quad*8]);
#pragma unroll
        for (int ni = 0; ni < NI; ni++)
            bfr[ni] = *reinterpret_cast<const bf16x8*>(&Bs[(wcol + ni*16 + col16)*32 + quad*8]);
#pragma unroll
        for (int mi = 0; mi < 4; mi++)
#pragma unroll
            for (int ni = 0; ni < NI; ni++)
                acc[mi][ni] = __builtin_amdgcn_mfma_f32_16x16x32_bf16(af[mi], bfr[ni], acc[mi][ni], 0, 0, 0);
        __syncthreads();
    }

    // epilogue: C/D layout col=lane&15, row=quad*4+reg
#pragma unroll
    for (int mi = 0; mi < 4; mi++) {
#pragma unroll
        for (int r = 0; r < 4; r++) {
            const int gm = bm + wrow + mi*16 + quad*4 + r;
            const int t  = gm & (TT - 1);
            const int b  = gm >> 11;          // TT = 2048
#pragma unroll
            for (int ni = 0; ni < NI; ni++) {
                const int gn = bn + wcol + ni*16 + col16;
                float v = acc[mi][ni][r];
                if (MODE == 2) {
                    reinterpret_cast<float*>(Cout)[(size_t)gm * N + gn] = v;
                } else {
                    const int which = gn >> 10;       // 0=Q 1=K 2=V
                    if (which == 0) v *= 0.18033688f; // 0.125 * log2(e), fp32 pre-rounding
                    const int n = gn & 1023;
                    const int h = n >> 6, d = n & 63;
                    const size_t off = (size_t)(which == 2 ? 3 : which) * MROWS * D_MODEL;
                    bf16_t* base = reinterpret_cast<bf16_t*>(Cout) + off;
                    base[(((size_t)(b*HEADS + h))*TT + t)*HD + d] = (bf16_t)v;
                }
            }
        }
    }
}

// ---------------- V transpose: [B,H,T,D] -> [B,H,D,T] ----------------
__global__ __launch_bounds__(256) void transpose_v(const bf16_t* __restrict__ V,
                                                   bf16_t* __restrict__ Vt) {
    __shared__ bf16_t tile[64][72];
    const int tid = threadIdx.x;
    const int bh = blockIdx.y;
    const int t0 = blockIdx.x * 64;
    const bf16_t* src = V + ((size_t)bh * TT + t0) * HD;
#pragma unroll
    for (int i = 0; i < 2; i++) {
        const int r = i*32 + (tid >> 3), c = (tid & 7) * 8;
        *reinterpret_cast<bf16x8*>(&tile[r][c]) =
            *reinterpret_cast<const bf16x8*>(&src[(size_t)r * HD + c]);
    }
    __syncthreads();
    bf16_t* dst = Vt + (size_t)bh * HD * TT + t0;
#pragma unroll
    for (int i = 0; i < 2; i++) {
        const int d = i*32 + (tid >> 3), tc = (tid & 7) * 8;
        bf16x8 o;
#pragma unroll
        for (int j = 0; j < 8; j++) o[j] = tile[tc + j][d];
        *reinterpret_cast<bf16x8*>(&dst[(size_t)d * TT + tc]) = o;
    }
}

// ---------------- flash attention: 4 waves/block, 64 q-rows, 64-key tiles ----
// R9: latency-bound fix (VALUBusy 48% incl. MFMA, occupancy 25% -> SIMDs >50%
// idle; makespan = longest block's 32 barrier-separated rounds).
// (a) Key-range SPLIT of qt 24..31 into two blocks (flash-decoding): max
//     serial chain 32 -> 24 rounds. No-max softmax => partials additive.
//     Halves write unnormalized O^T + lsum to global slots via agent-scope
//     atomic stores; per-pair counter (ACQ_REL RMW) -> second arriver merges,
//     normalizes, writes O. Release/acquire via RMW = XCD-coherence-safe.
// (b) 40 blocks/bh -> grid 1280 = 5 blocks/CU (LDS 5x32KB = 160KB exactly,
//     __launch_bounds__(256,5)): occupancy 16 -> 20 waves/CU. Table TQT/TK0/
//     TK1: every CU-set of 5 sums to 66 rounds.
// R8 permlane PV redistribution + S^T formulation retained.
__global__ __launch_bounds__(256, 5) void attn_kernel(const bf16_t* __restrict__ Q,
                                                      const bf16_t* __restrict__ Kk,
                                                      const bf16_t* __restrict__ Vt,
                                                      bf16_t* __restrict__ O,
                                                      float* __restrict__ Opart,
                                                      float* __restrict__ Lpart,
                                                      unsigned int* __restrict__ cnt) {
    __shared__ __align__(16) bf16_t Ks[2][64*64];   // [key][d-chunks], XOR-swizzled
    __shared__ __align__(16) bf16_t Vs[2][64*64];   // [d][key-chunks], XOR-swizzled

    const int tid   = threadIdx.x;
    const int lane  = tid & 63;
    const int wave  = tid >> 6;
    const int col16 = lane & 15;
    const int quad  = lane >> 4;
    const int kw    = wave & 1;    // key-half this wave owns (keys kw*32..kw*32+31)
    const int qw    = wave >> 1;   // query-half this wave owns (rows qb+qw*32..+31)

    const int bx = blockIdx.x;
    const int r_ = bx >> 8, s_ = bx & 255;
    const int bh = s_ & 31;
    const int g  = s_ >> 5;
    const int qt = TQT[g][r_];
    const int k0 = TK0[g][r_];
    const int k1 = TK1[g][r_];
    const bool split = (qt >= 24);
    const int qb    = qt * 64;
    const int qbase = qb + qw * 32;

    const bf16_t* Qb = Q  + (size_t)bh * TT * HD;
    const bf16_t* Kb = Kk + (size_t)bh * TT * HD;
    const bf16_t* Vb = Vt + (size_t)bh * HD * TT;

    // Q fragments (B-operand layout B[k=d][n=q]) for both 16-row query groups
    bf16x8 qf[2][2];
#pragma unroll
    for (int qg = 0; qg < 2; qg++)
#pragma unroll
        for (int h = 0; h < 2; h++)
            qf[qg][h] = *reinterpret_cast<const bf16x8*>(
                &Qb[(size_t)(qbase + qg*16 + col16)*HD + h*32 + quad*8]);

    // staging geometry: each shot = 256 threads x 16B = 4KB = 32 rows x 64 cols.
    // LDS[row*64 + ch*8 + i] = src[row][(ch ^ (row&7))*8 + i]  (XOR swizzle).
    const int srow = (tid >> 3) & 31;
    const int sg   = ((lane & 7) ^ (srow & 7)) * 8;

    auto stage = [&](int kt, int buf) {
        const int s0 = kt * 64;
        GLDS16(&Kb[(size_t)(s0 + srow)*HD + sg],        &Ks[buf][wave*512]);
        GLDS16(&Kb[(size_t)(s0 + srow + 32)*HD + sg],   &Ks[buf][2048 + wave*512]);
        GLDS16(&Vb[(size_t)srow*TT + s0 + sg],          &Vs[buf][wave*512]);
        GLDS16(&Vb[(size_t)(srow + 32)*TT + s0 + sg],   &Vs[buf][2048 + wave*512]);
    };

    // out^T partial over this wave's key half:
    // acc[c][qg][r] = O^T[d = c*16+quad*4+r][q = qg*16+col16]
    f32x4 acc[4][2];
#pragma unroll
    for (int i = 0; i < 4; i++)
#pragma unroll
        for (int j = 0; j < 2; j++) acc[i][j] = (f32x4){0.f,0.f,0.f,0.f};
    float lsum[2] = {0.f, 0.f};     // partial softmax denoms (this key half)

    const int x7 = col16 & 7;

    stage(k0, 0);
    __syncthreads();

    int buf = 0;
    for (int kt = k0; kt < k1; kt++) {
        if (kt + 1 < k1) stage(kt + 1, buf ^ 1);    // async prefetch, drained by end barrier
        const int s0 = kt * 64;
        const bool diag = (kt == qt);

        // ---- S^T = K Q^T on this wave's 32 keys x 32 queries ----
        bf16x8 kf0[2], kf1[2];
#pragma unroll
        for (int c = 0; c < 2; c++) {
            // K A-frag: A[m=key][k=d]: lane holds K[s0+kw*32+c*16+col16][d-chunk]
            kf0[c] = *reinterpret_cast<const bf16x8*>(
                &Ks[buf][(kw*32 + c*16 + col16)*64 + ((0*4 + quad) ^ x7)*8]);
            kf1[c] = *reinterpret_cast<const bf16x8*>(
                &Ks[buf][(kw*32 + c*16 + col16)*64 + ((1*4 + quad) ^ x7)*8]);
        }

        int pk[2][2][2];   // pk[c][qg][x]: keys kw*32+c*16+quad*4+{2x,2x+1}, query qg*16+col16
#pragma unroll
        for (int c = 0; c < 2; c++) {
#pragma unroll
            for (int qg = 0; qg < 2; qg++) {
                f32x4 sv = __builtin_amdgcn_mfma_f32_16x16x32_bf16(kf0[c], qf[qg][0], (f32x4){0.f,0.f,0.f,0.f}, 0, 0, 0);
                sv       = __builtin_amdgcn_mfma_f32_16x16x32_bf16(kf1[c], qf[qg][1], sv, 0, 0, 0);

                float pr[4];
#pragma unroll
                for (int r = 0; r < 4; r++) pr[r] = exp2f(sv[r]);   // scale baked into Q
                if (diag) {   // causal mask, block-uniform branch
#pragma unroll
                    for (int r = 0; r < 4; r++)
                        if (s0 + kw*32 + c*16 + quad*4 + r > qbase + qg*16 + col16) pr[r] = 0.f;
                }
                lsum[qg] += (pr[0] + pr[1]) + (pr[2] + pr[3]);
                pk[c][qg][0] = pack_bf16(pr[0], pr[1]);
                pk[c][qg][1] = pack_bf16(pr[2], pr[3]);
            }
        }

        // ---- PV: out^T += V^T P^T over this wave's 32-key chunk ----
        bf16x8 pf[2];
#pragma unroll
        for (int qg = 0; qg < 2; qg++) {
#if __has_builtin(__builtin_amdgcn_permlane32_swap)
            i32x2 u0 = __builtin_amdgcn_permlane32_swap(pk[0][qg][0], pk[1][qg][0], false, false);
            i32x2 v0 = __builtin_amdgcn_permlane16_swap(u0[0], u0[1], false, false);
            i32x2 u1 = __builtin_amdgcn_permlane32_swap(pk[0][qg][1], pk[1][qg][1], false, false);
            i32x2 v1 = __builtin_amdgcn_permlane16_swap(u1[0], u1[1], false, false);
            int4 bi = { v0[0], v1[0], v0[1], v1[1] };   // slots 0,1,2,3
#else
            const int a1 = ((quad & 1) * 32 + col16) * 4;
            const int a2 = a1 + 64;
            const bool hi = quad >= 2;
            int b0l = __builtin_amdgcn_ds_bpermute(a1, pk[0][qg][0]);
            int b0h = __builtin_amdgcn_ds_bpermute(a1, pk[1][qg][0]);
            int b1l = __builtin_amdgcn_ds_bpermute(a1, pk[0][qg][1]);
            int b1h = __builtin_amdgcn_ds_bpermute(a1, pk[1][qg][1]);
            int b2l = __builtin_amdgcn_ds_bpermute(a2, pk[0][qg][0]);
            int b2h = __builtin_amdgcn_ds_bpermute(a2, pk[1][qg][0]);
            int b3l = __builtin_amdgcn_ds_bpermute(a2, pk[0][qg][1]);
            int b3h = __builtin_amdgcn_ds_bpermute(a2, pk[1][qg][1]);
            int4 bi = { hi ? b0h : b0l, hi ? b1h : b1l, hi ? b2h : b2l, hi ? b3h : b3l };
#endif
            pf[qg] = __builtin_bit_cast(bf16x8, bi);
        }
#pragma unroll
        for (int c = 0; c < 4; c++) {
            // V^T A-frag: A[m=d][k=key]: lane holds V^T[c*16+col16][s0+kw*32+quad*8+j]
            bf16x8 vf = *reinterpret_cast<const bf16x8*>(
                &Vs[buf][(c*16 + col16)*64 + ((kw*4 + quad) ^ x7)*8]);
            acc[c][0] = __builtin_amdgcn_mfma_f32_16x16x32_bf16(vf, pf[0], acc[c][0], 0, 0, 0);
            acc[c][1] = __builtin_amdgcn_mfma_f32_16x16x32_bf16(vf, pf[1], acc[c][1], 0, 0, 0);
        }
        buf ^= 1;
        __syncthreads();   // drains prefetch (vmcnt0) + protects LDS buffers
    }

    // partial denoms: sum across quads (same query col16) within the wave
#pragma unroll
    for (int qg = 0; qg < 2; qg++) {
        lsum[qg] += __shfl_xor(lsum[qg], 16);
        lsum[qg] += __shfl_xor(lsum[qg], 32);
    }

    // ---- cross-kw merge (partials are additive: no-max softmax) ----
    // kw=1 waves park their partials in LDS (K/V buffers are released by the
    // final loop barrier); qw selects the buffer. Layout: M[32 q][68 d] f32.
    float* Mq = qw ? reinterpret_cast<float*>(&Vs[0][0])
                   : reinterpret_cast<float*>(&Ks[0][0]);
    float* LS = reinterpret_cast<float*>(&Vs[0][0]) + 32*68;   // 64 denom slots

    if (kw == 1) {
#pragma unroll
        for (int c = 0; c < 4; c++)
#pragma unroll
            for (int qg = 0; qg < 2; qg++)
                *reinterpret_cast<f32x4*>(&Mq[(qg*16 + col16)*68 + c*16 + quad*4]) = acc[c][qg];
        if (lane < 16) {
            LS[qw*32 + lane]      = lsum[0];
            LS[qw*32 + 16 + lane] = lsum[1];
        }
    }
    __syncthreads();

    const int b_ = bh >> 4, h = bh & 15;
    const int p  = bh * 8 + (qt - 24);          // valid only when split
    if (kw == 0) {
        const int half = (k0 == 0) ? 0 : 1;
        float* Op = Opart + ((size_t)p * 2 + half) * 4096;
        float* Lp = Lpart + ((size_t)p * 2 + half) * 64;
#pragma unroll
        for (int qg = 0; qg < 2; qg++) {
            const float l  = lsum[qg] + LS[qw*32 + qg*16 + col16];
            const int   ql = qw*32 + qg*16 + col16;
            if (!split) {
                const float inv = 1.0f / l;
                const int t = qb + ql;
                bf16_t* Ob = &O[(((size_t)(b_*TT + t))*HEADS + h)*HD + quad*4];
#pragma unroll
                for (int c = 0; c < 4; c++) {
                    f32x4 m = *reinterpret_cast<const f32x4*>(&Mq[(qg*16 + col16)*68 + c*16 + quad*4]);
                    bf16x4 o4;
#pragma unroll
                    for (int r = 0; r < 4; r++) o4[r] = (bf16_t)((acc[c][qg][r] + m[r]) * inv);
                    *reinterpret_cast<bf16x4*>(&Ob[c*16]) = o4;
                }
            } else {
                if (quad == 0)
                    __hip_atomic_store(&Lp[ql], l, __ATOMIC_RELAXED, __HIP_MEMORY_SCOPE_AGENT);
#pragma unroll
                for (int c = 0; c < 4; c++) {
                    f32x4 m = *reinterpret_cast<const f32x4*>(&Mq[(qg*16 + col16)*68 + c*16 + quad*4]);
#pragma unroll
                    for (int r = 0; r < 4; r++)
                        __hip_atomic_store(&Op[ql*64 + c*16 + quad*4 + r], acc[c][qg][r] + m[r],
                                           __ATOMIC_RELAXED, __HIP_MEMORY_SCOPE_AGENT);
                }
            }
        }
    }

    if (split) {
        // handshake: second arriver merges (release/acquire via ACQ_REL RMW)
        int* wf = reinterpret_cast<int*>(reinterpret_cast<char*>(&Ks[0][0]) + 12288);
        __syncthreads();                 // all partial stores issued + vmcnt drained
        if (tid == 0) {
            unsigned int old = __hip_atomic_fetch_add(&cnt[p], 1u, __ATOMIC_ACQ_REL,
                                                      __HIP_MEMORY_SCOPE_AGENT);
            *wf = (old == 1);
        }
        __syncthreads();
        if (*wf) {
            const float* O0 = Opart + (size_t)p * 2 * 4096;
            const float* O1 = O0 + 4096;
            const float* L0 = Lpart + (size_t)p * 2 * 64;
            const float* L1 = L0 + 64;
            const int q  = tid >> 2;            // 0..63
            const int d0 = (tid & 3) * 16;
            const float l = __hip_atomic_load(&L0[q], __ATOMIC_RELAXED, __HIP_MEMORY_SCOPE_AGENT)
                          + __hip_atomic_load(&L1[q], __ATOMIC_RELAXED, __HIP_MEMORY_SCOPE_AGENT);
            const float inv = 1.0f / l;
            const int t = qb + q;
            bf16_t* Ob = &O[(((size_t)(b_*TT + t))*HEADS + h)*HD + d0];
#pragma unroll
            for (int j = 0; j < 16; j += 4) {
                bf16x4 o4;
#pragma unroll
                for (int rr = 0; rr < 4; rr++) {
                    const int idx = q*64 + d0 + j + rr;
                    float a = __hip_atomic_load(&O0[idx], __ATOMIC_RELAXED, __HIP_MEMORY_SCOPE_AGENT)
                            + __hip_atomic_load(&O1[idx], __ATOMIC_RELAXED, __HIP_MEMORY_SCOPE_AGENT);
                    o4[rr] = (bf16_t)(a * inv);
                }
                *reinterpret_cast<bf16x4*>(&Ob[j]) = o4;
            }
        }
    }
}

// ---------------- launch ----------------
extern "C" void kernel_launch(void* const* d_in, const int* in_sizes, int n_in,
                              void* d_out, int out_size, void* d_ws, size_t ws_size,
                              hipStream_t stream) {
    const float* x  = (const float*)d_in[0];
    const float* Wq = (const float*)d_in[1];
    const float* Wk = (const float*)d_in[2];
    const float* Wv = (const float*)d_in[3];
    const float* Wo = (const float*)d_in[4];
    float* out = (float*)d_out;

    // workspace layout (bf16 elements), contiguous, 48 MB + 132 KB
    bf16_t* Xb  = (bf16_t*)d_ws;                       // 4M
    bf16_t* Wqb = Xb  + (size_t)MROWS * D_MODEL;       // 3M (Wq|Wk|Wv)
    bf16_t* Wob = Wqb + (size_t)3 * D_MODEL * D_MODEL; // 1M
    bf16_t* Qw  = Wob + (size_t)D_MODEL * D_MODEL;     // 4M  [B,H,T,D], pre-scaled
    bf16_t* Kw  = Qw  + (size_t)MROWS * D_MODEL;       // 4M  [B,H,T,D]
    bf16_t* Vt  = Kw  + (size_t)MROWS * D_MODEL;       // 4M  [B,H,D,T]
    bf16_t* Ow  = Vt  + (size_t)MROWS * D_MODEL;       // 4M  V-raw, then attn out [B,T,H,D]
    // split-merge scratch: Opart aliases Xb (dead during attn); cnt/Lpart at +48MB
    float*        Opart = (float*)Xb;                  // 256 pairs x 2 x 4096 f32 = 8 MiB
    unsigned int* cnt   = (unsigned int*)((char*)d_ws + (size_t)48*1024*1024);  // 1 KiB
    float*        Lpart = (float*)((char*)d_ws + (size_t)48*1024*1024 + 1024);  // 128 KiB

    // 1) convert all inputs to bf16 (+ zero the 256 split-merge counters)
    cvt_all_kernel<<<(MROWS*D_MODEL + 4*D_MODEL*D_MODEL) / 4 / 256, 256, 0, stream>>>(
        x, Wq, Wk, Wv, Wo, Xb, cnt);

    // 2) fused QKV projection (V-raw lands in the Ow slot, coalesced)
    dim3 gqkv(3 * D_MODEL / 128, MROWS / 128);
    gemm_bt<0,128><<<gqkv, 256, 0, stream>>>(Xb, Wqb, Qw, MROWS, 3 * D_MODEL, D_MODEL);

    // 3) V transpose -> [B,H,D,T]
    dim3 gt(TT / 64, BB * HEADS);
    transpose_v<<<gt, 256, 0, stream>>>(Ow, Vt);

    // 4) flash attention; 1280 blocks = 5/CU (overwrites Ow with [B,T,H,D] out)
    attn_kernel<<<dim3(1280), 256, 0, stream>>>(Qw, Kw, Vt, Ow, Opart, Lpart, cnt);

    // 5) output projection -> fp32 d_out (64-col tiles: 512 blocks = 2/CU)
    dim3 go(D_MODEL / 64, MROWS / 128);
    gemm_bt<2,64><<<go, 256, 0, stream>>>(Ow, Wob, out, MROWS, D_MODEL, D_MODEL);
}

// Round 6
// 204.838 us; speedup vs baseline: 1.1079x; 1.1079x over previous
//
#include <hip/hip_runtime.h>
#include <hip/hip_bf16.h>

// ---- types ----
typedef __bf16 bf16_t;
typedef __bf16 bf16x2 __attribute__((ext_vector_type(2)));
typedef __bf16 bf16x4 __attribute__((ext_vector_type(4)));
typedef __bf16 bf16x8 __attribute__((ext_vector_type(8)));
typedef float  f32x4  __attribute__((ext_vector_type(4)));
typedef int    i32x2  __attribute__((ext_vector_type(2)));

#define D_MODEL 1024
#define HEADS   16
#define HD      64
#define BB      2
#define TT      2048
#define MROWS   (BB*TT)   // 4096

#define GLDS16(g, l) __builtin_amdgcn_global_load_lds( \
    (const __attribute__((address_space(1))) void*)(g), \
    (__attribute__((address_space(3))) void*)(l), 16, 0, 0)

static __device__ __forceinline__ int pack_bf16(float a, float b) {
    bf16x2 t; t[0] = (bf16_t)a; t[1] = (bf16_t)b;
    return __builtin_bit_cast(int, t);
}

// ---------------- fused fp32 -> bf16 convert (+ zero split-merge counters) ----
__global__ __launch_bounds__(256) void cvt_all_kernel(const float* __restrict__ x,
                                                      const float* __restrict__ wq,
                                                      const float* __restrict__ wk,
                                                      const float* __restrict__ wv,
                                                      const float* __restrict__ wo,
                                                      bf16_t* __restrict__ dst,
                                                      unsigned int* __restrict__ cnt) {
    if (blockIdx.x == 0) cnt[threadIdx.x] = 0;      // 256 pair counters
    const int i = blockIdx.x * 256 + threadIdx.x;   // vec4 index, total 2097152
    const float* src;
    int s;
    if (i < 1048576) { src = x; s = i; }
    else {
        int j = i - 1048576;
        int w = j >> 18;          // 262144 vec4 per weight
        s = j & 262143;
        src = (w == 0) ? wq : (w == 1) ? wk : (w == 2) ? wv : wo;
    }
    float4 v = reinterpret_cast<const float4*>(src)[s];
    bf16x4 o;
    o[0] = (bf16_t)v.x; o[1] = (bf16_t)v.y; o[2] = (bf16_t)v.z; o[3] = (bf16_t)v.w;
    reinterpret_cast<bf16x4*>(dst)[i] = o;
}

// ---------------- bf16 GEMM: C[M,N] = A[M,K] * B[N,K]^T ----------------
// BN = 128 or 64 (N-tile). M-tile fixed 128.
// MODE 0: fused QKV scatter (N=3072) -> [B,H,T,D] each; Q at Cout+0 (pre-scaled
//         by 0.125*log2e in fp32 before bf16 rounding), K at +4M, V at +12M
//         elements (the Ow slot, later transposed to Vt).
// MODE 2: fp32 row-major [M,N] (final output)
template<int MODE, int BN>
__global__ __launch_bounds__(256) void gemm_bt(const bf16_t* __restrict__ A,
                                               const bf16_t* __restrict__ Bw,
                                               void* __restrict__ Cout,
                                               int M, int N, int K) {
    constexpr int NI = BN / 32;     // n-tiles of 16 per wave
    __shared__ __align__(16) bf16_t As[128*32];
    __shared__ __align__(16) bf16_t Bs[BN*32];
    const int tid   = threadIdx.x;
    const int lane  = tid & 63;
    const int wave  = tid >> 6;
    const int col16 = lane & 15;
    const int quad  = lane >> 4;
    const int wrow  = (wave & 1) * 64;
    const int wcol  = (wave >> 1) * (BN / 2);
    const int bm    = blockIdx.y * 128;
    const int bn    = blockIdx.x * BN;

    const int lr = tid >> 2;        // 0..63
    const int lc = (tid & 3) * 8;   // 0,8,16,24

    const bf16_t* agp = &A [(size_t)(bm + lr)*K + lc];
    const bf16_t* bgp = &Bw[(size_t)(bn + lr)*K + lc];
    const size_t half = (size_t)64 * K;
    bf16_t* as_lo = &As[wave*512];
    bf16_t* as_hi = &As[2048 + wave*512];
    bf16_t* bs_lo = &Bs[wave*512];
    bf16_t* bs_hi = &Bs[2048 + wave*512];   // only used when BN==128

    f32x4 acc[4][NI];
#pragma unroll
    for (int i = 0; i < 4; i++)
#pragma unroll
        for (int j = 0; j < NI; j++) acc[i][j] = (f32x4){0.f, 0.f, 0.f, 0.f};

    for (int k0 = 0; k0 < K; k0 += 32) {
        GLDS16(agp + k0,        as_lo);
        GLDS16(agp + half + k0, as_hi);
        GLDS16(bgp + k0,        bs_lo);
        if (BN == 128) GLDS16(bgp + half + k0, bs_hi);
        __syncthreads();

        bf16x8 af[4], bfr[NI];
#pragma unroll
        for (int mi = 0; mi < 4; mi++)
            af[mi] = *reinterpret_cast<const bf16x8*>(&As[(wrow + mi*16 + col16)*32 + quad*8]);
#pragma unroll
        for (int ni = 0; ni < NI; ni++)
            bfr[ni] = *reinterpret_cast<const bf16x8*>(&Bs[(wcol + ni*16 + col16)*32 + quad*8]);
#pragma unroll
        for (int mi = 0; mi < 4; mi++)
#pragma unroll
            for (int ni = 0; ni < NI; ni++)
                acc[mi][ni] = __builtin_amdgcn_mfma_f32_16x16x32_bf16(af[mi], bfr[ni], acc[mi][ni], 0, 0, 0);
        __syncthreads();
    }

    // epilogue: C/D layout col=lane&15, row=quad*4+reg
#pragma unroll
    for (int mi = 0; mi < 4; mi++) {
#pragma unroll
        for (int r = 0; r < 4; r++) {
            const int gm = bm + wrow + mi*16 + quad*4 + r;
            const int t  = gm & (TT - 1);
            const int b  = gm >> 11;          // TT = 2048
#pragma unroll
            for (int ni = 0; ni < NI; ni++) {
                const int gn = bn + wcol + ni*16 + col16;
                float v = acc[mi][ni][r];
                if (MODE == 2) {
                    reinterpret_cast<float*>(Cout)[(size_t)gm * N + gn] = v;
                } else {
                    const int which = gn >> 10;       // 0=Q 1=K 2=V
                    if (which == 0) v *= 0.18033688f; // 0.125 * log2(e), fp32 pre-rounding
                    const int n = gn & 1023;
                    const int h = n >> 6, d = n & 63;
                    const size_t off = (size_t)(which == 2 ? 3 : which) * MROWS * D_MODEL;
                    bf16_t* base = reinterpret_cast<bf16_t*>(Cout) + off;
                    base[(((size_t)(b*HEADS + h))*TT + t)*HD + d] = (bf16_t)v;
                }
            }
        }
    }
}

// ---------------- V transpose: [B,H,T,D] -> [B,H,D,T] ----------------
__global__ __launch_bounds__(256) void transpose_v(const bf16_t* __restrict__ V,
                                                   bf16_t* __restrict__ Vt) {
    __shared__ bf16_t tile[64][72];
    const int tid = threadIdx.x;
    const int bh = blockIdx.y;
    const int t0 = blockIdx.x * 64;
    const bf16_t* src = V + ((size_t)bh * TT + t0) * HD;
#pragma unroll
    for (int i = 0; i < 2; i++) {
        const int r = i*32 + (tid >> 3), c = (tid & 7) * 8;
        *reinterpret_cast<bf16x8*>(&tile[r][c]) =
            *reinterpret_cast<const bf16x8*>(&src[(size_t)r * HD + c]);
    }
    __syncthreads();
    bf16_t* dst = Vt + (size_t)bh * HD * TT + t0;
#pragma unroll
    for (int i = 0; i < 2; i++) {
        const int d = i*32 + (tid >> 3), tc = (tid & 7) * 8;
        bf16x8 o;
#pragma unroll
        for (int j = 0; j < 8; j++) o[j] = tile[tc + j][d];
        *reinterpret_cast<bf16x8*>(&dst[(size_t)d * TT + tc]) = o;
    }
}

// ---------------- flash attention: 4 waves/block, 64 q-rows, 64-key tiles ----
// R10: R8 envelope (grid 1024, 4 blocks/CU, 128KB LDS) + balanced schedule
// with splits, closed-form (no tables):
//   r_=0: unsplit qt=23-g                        (17..24 rounds)
//   r_=1: first  key-half of qt=24+g             (12..16 rounds, no diag)
//   r_=2: second key-half of qt=24+g             (13..16 rounds, has diag)
//   r_=3: sequential pair qt=g then qt=15-g      (17 rounds total, no merge)
// Every CU-set of 4 (stride-256 cyclic dispatch, shared bh) sums to exactly
// 66 rounds; max serial chain 24 (was 32).
// R9 lesson: split partials move via PLAIN f32x4 stores/loads ([q][d] layout,
// 64B segments) — R9's per-element scalar atomics turned 8MB of partials into
// ~38MB of uncoalesced HBM writes (WRITE_SIZE 46MB, +35us). The ACQ_REL
// agent-scope fetch_add handshake (proven correct in R9) provides the
// release/acquire ordering; second arriver merges and writes O.
// R8 permlane PV redistribution + S^T formulation retained.
__global__ __launch_bounds__(256, 4) void attn_kernel(const bf16_t* __restrict__ Q,
                                                      const bf16_t* __restrict__ Kk,
                                                      const bf16_t* __restrict__ Vt,
                                                      bf16_t* __restrict__ O,
                                                      float* __restrict__ Opart,
                                                      float* __restrict__ Lpart,
                                                      unsigned int* __restrict__ cnt) {
    __shared__ __align__(16) bf16_t Ks[2][64*64];   // [key][d-chunks], XOR-swizzled
    __shared__ __align__(16) bf16_t Vs[2][64*64];   // [d][key-chunks], XOR-swizzled

    const int tid   = threadIdx.x;
    const int lane  = tid & 63;
    const int wave  = tid >> 6;
    const int col16 = lane & 15;
    const int quad  = lane >> 4;
    const int kw    = wave & 1;    // key-half this wave owns (keys kw*32..kw*32+31)
    const int qw    = wave >> 1;   // query-half this wave owns

    const int bx = blockIdx.x;
    const int r_ = bx >> 8, s_ = bx & 255;
    const int bh = s_ & 31;
    const int g  = s_ >> 5;
    const int b_ = bh >> 4, h = bh & 15;
    const int nseg = (r_ == 3) ? 2 : 1;

    const bf16_t* Qb = Q  + (size_t)bh * TT * HD;
    const bf16_t* Kb = Kk + (size_t)bh * TT * HD;
    const bf16_t* Vb = Vt + (size_t)bh * HD * TT;

    // staging geometry: each shot = 256 threads x 16B = 4KB = 32 rows x 64 cols.
    // LDS[row*64 + ch*8 + i] = src[row][(ch ^ (row&7))*8 + i]  (XOR swizzle).
    const int srow = (tid >> 3) & 31;
    const int sg   = ((lane & 7) ^ (srow & 7)) * 8;
    const int x7   = col16 & 7;

    auto stage = [&](int kt, int buf) {
        const int s0 = kt * 64;
        GLDS16(&Kb[(size_t)(s0 + srow)*HD + sg],        &Ks[buf][wave*512]);
        GLDS16(&Kb[(size_t)(s0 + srow + 32)*HD + sg],   &Ks[buf][2048 + wave*512]);
        GLDS16(&Vb[(size_t)srow*TT + s0 + sg],          &Vs[buf][wave*512]);
        GLDS16(&Vb[(size_t)(srow + 32)*TT + s0 + sg],   &Vs[buf][2048 + wave*512]);
    };

    for (int seg = 0; seg < nseg; seg++) {
        int qt, k0, k1, half;
        bool split = false;
        if (r_ == 0)      { qt = 23 - g;          k0 = 0;             k1 = qt + 1;        half = 0; }
        else if (r_ == 1) { qt = 24 + g;          k0 = 0;             k1 = (qt + 1) >> 1; half = 0; split = true; }
        else if (r_ == 2) { qt = 24 + g;          k0 = (qt + 1) >> 1; k1 = qt + 1;        half = 1; split = true; }
        else              { qt = seg ? (15 - g) : g; k0 = 0;          k1 = qt + 1;        half = 0; }

        const int qb    = qt * 64;
        const int qbase = qb + qw * 32;

        // Q fragments (B-operand layout B[k=d][n=q]) for both 16-row query groups
        bf16x8 qf[2][2];
#pragma unroll
        for (int qg = 0; qg < 2; qg++)
#pragma unroll
            for (int hh = 0; hh < 2; hh++)
                qf[qg][hh] = *reinterpret_cast<const bf16x8*>(
                    &Qb[(size_t)(qbase + qg*16 + col16)*HD + hh*32 + quad*8]);

        // out^T partial: acc[c][qg][r] = O^T[d = c*16+quad*4+r][q = qg*16+col16]
        f32x4 acc[4][2];
#pragma unroll
        for (int i = 0; i < 4; i++)
#pragma unroll
            for (int j = 0; j < 2; j++) acc[i][j] = (f32x4){0.f,0.f,0.f,0.f};
        float lsum[2] = {0.f, 0.f};

        if (seg) __syncthreads();   // protect LDS epilogue area of seg 0
        stage(k0, 0);
        __syncthreads();

        int buf = 0;
        for (int kt = k0; kt < k1; kt++) {
            if (kt + 1 < k1) stage(kt + 1, buf ^ 1);   // async prefetch, drained by end barrier
            const int s0 = kt * 64;
            const bool diag = (kt == qt);

            // ---- S^T = K Q^T on this wave's 32 keys x 32 queries ----
            bf16x8 kf0[2], kf1[2];
#pragma unroll
            for (int c = 0; c < 2; c++) {
                kf0[c] = *reinterpret_cast<const bf16x8*>(
                    &Ks[buf][(kw*32 + c*16 + col16)*64 + ((0*4 + quad) ^ x7)*8]);
                kf1[c] = *reinterpret_cast<const bf16x8*>(
                    &Ks[buf][(kw*32 + c*16 + col16)*64 + ((1*4 + quad) ^ x7)*8]);
            }

            int pk[2][2][2];   // pk[c][qg][x]: keys kw*32+c*16+quad*4+{2x,2x+1}, query qg*16+col16
#pragma unroll
            for (int c = 0; c < 2; c++) {
#pragma unroll
                for (int qg = 0; qg < 2; qg++) {
                    f32x4 sv = __builtin_amdgcn_mfma_f32_16x16x32_bf16(kf0[c], qf[qg][0], (f32x4){0.f,0.f,0.f,0.f}, 0, 0, 0);
                    sv       = __builtin_amdgcn_mfma_f32_16x16x32_bf16(kf1[c], qf[qg][1], sv, 0, 0, 0);

                    float pr[4];
#pragma unroll
                    for (int r = 0; r < 4; r++) pr[r] = exp2f(sv[r]);   // scale baked into Q
                    if (diag) {   // causal mask, block-uniform branch
#pragma unroll
                        for (int r = 0; r < 4; r++)
                            if (s0 + kw*32 + c*16 + quad*4 + r > qbase + qg*16 + col16) pr[r] = 0.f;
                    }
                    lsum[qg] += (pr[0] + pr[1]) + (pr[2] + pr[3]);
                    pk[c][qg][0] = pack_bf16(pr[0], pr[1]);
                    pk[c][qg][1] = pack_bf16(pr[2], pr[3]);
                }
            }

            // ---- PV: out^T += V^T P^T over this wave's 32-key chunk ----
            bf16x8 pf[2];
#pragma unroll
            for (int qg = 0; qg < 2; qg++) {
#if __has_builtin(__builtin_amdgcn_permlane32_swap)
                i32x2 u0 = __builtin_amdgcn_permlane32_swap(pk[0][qg][0], pk[1][qg][0], false, false);
                i32x2 v0 = __builtin_amdgcn_permlane16_swap(u0[0], u0[1], false, false);
                i32x2 u1 = __builtin_amdgcn_permlane32_swap(pk[0][qg][1], pk[1][qg][1], false, false);
                i32x2 v1 = __builtin_amdgcn_permlane16_swap(u1[0], u1[1], false, false);
                int4 bi = { v0[0], v1[0], v0[1], v1[1] };   // slots 0,1,2,3
#else
                const int a1 = ((quad & 1) * 32 + col16) * 4;
                const int a2 = a1 + 64;
                const bool hi = quad >= 2;
                int b0l = __builtin_amdgcn_ds_bpermute(a1, pk[0][qg][0]);
                int b0h = __builtin_amdgcn_ds_bpermute(a1, pk[1][qg][0]);
                int b1l = __builtin_amdgcn_ds_bpermute(a1, pk[0][qg][1]);
                int b1h = __builtin_amdgcn_ds_bpermute(a1, pk[1][qg][1]);
                int b2l = __builtin_amdgcn_ds_bpermute(a2, pk[0][qg][0]);
                int b2h = __builtin_amdgcn_ds_bpermute(a2, pk[1][qg][0]);
                int b3l = __builtin_amdgcn_ds_bpermute(a2, pk[0][qg][1]);
                int b3h = __builtin_amdgcn_ds_bpermute(a2, pk[1][qg][1]);
                int4 bi = { hi ? b0h : b0l, hi ? b1h : b1l, hi ? b2h : b2l, hi ? b3h : b3l };
#endif
                pf[qg] = __builtin_bit_cast(bf16x8, bi);
            }
#pragma unroll
            for (int c = 0; c < 4; c++) {
                bf16x8 vf = *reinterpret_cast<const bf16x8*>(
                    &Vs[buf][(c*16 + col16)*64 + ((kw*4 + quad) ^ x7)*8]);
                acc[c][0] = __builtin_amdgcn_mfma_f32_16x16x32_bf16(vf, pf[0], acc[c][0], 0, 0, 0);
                acc[c][1] = __builtin_amdgcn_mfma_f32_16x16x32_bf16(vf, pf[1], acc[c][1], 0, 0, 0);
            }
            buf ^= 1;
            __syncthreads();   // drains prefetch (vmcnt0) + protects LDS buffers
        }

        // partial denoms: sum across quads (same query col16) within the wave
#pragma unroll
        for (int qg = 0; qg < 2; qg++) {
            lsum[qg] += __shfl_xor(lsum[qg], 16);
            lsum[qg] += __shfl_xor(lsum[qg], 32);
        }

        // ---- cross-kw merge in LDS (partials additive: no-max softmax) ----
        float* Mq = qw ? reinterpret_cast<float*>(&Vs[0][0])
                       : reinterpret_cast<float*>(&Ks[0][0]);
        float* LS = reinterpret_cast<float*>(&Vs[0][0]) + 32*68;   // 64 denom slots

        if (kw == 1) {
#pragma unroll
            for (int c = 0; c < 4; c++)
#pragma unroll
                for (int qg = 0; qg < 2; qg++)
                    *reinterpret_cast<f32x4*>(&Mq[(qg*16 + col16)*68 + c*16 + quad*4]) = acc[c][qg];
            if (lane < 16) {
                LS[qw*32 + lane]      = lsum[0];
                LS[qw*32 + 16 + lane] = lsum[1];
            }
        }
        __syncthreads();

        const int p = bh * 8 + (qt - 24);         // valid only when split
        if (kw == 0) {
            float* Op = Opart + ((size_t)p * 2 + half) * 4096;
            float* Lp = Lpart + ((size_t)p * 2 + half) * 64;
#pragma unroll
            for (int qg = 0; qg < 2; qg++) {
                const float l  = lsum[qg] + LS[qw*32 + qg*16 + col16];
                const int   ql = qw*32 + qg*16 + col16;
                if (!split) {
                    const float inv = 1.0f / l;
                    const int t = qb + ql;
                    bf16_t* Ob = &O[(((size_t)(b_*TT + t))*HEADS + h)*HD + quad*4];
#pragma unroll
                    for (int c = 0; c < 4; c++) {
                        f32x4 m = *reinterpret_cast<const f32x4*>(&Mq[(qg*16 + col16)*68 + c*16 + quad*4]);
                        bf16x4 o4;
#pragma unroll
                        for (int r = 0; r < 4; r++) o4[r] = (bf16_t)((acc[c][qg][r] + m[r]) * inv);
                        *reinterpret_cast<bf16x4*>(&Ob[c*16]) = o4;
                    }
                } else {
                    if (quad == 0) Lp[ql] = l;
                    // [q][d] layout: lane writes f32x4 at d = c*16+quad*4 (64B/quad-group)
#pragma unroll
                    for (int c = 0; c < 4; c++) {
                        f32x4 m = *reinterpret_cast<const f32x4*>(&Mq[(qg*16 + col16)*68 + c*16 + quad*4]);
                        f32x4 o = acc[c][qg];
#pragma unroll
                        for (int r = 0; r < 4; r++) o[r] += m[r];
                        *reinterpret_cast<f32x4*>(&Op[(size_t)ql*64 + c*16 + quad*4]) = o;
                    }
                }
            }
        }

        if (split) {
            // handshake: second arriver merges (release/acquire via ACQ_REL RMW)
            int* wf = reinterpret_cast<int*>(reinterpret_cast<char*>(&Ks[0][0]) + 12288);
            __syncthreads();                 // all partial stores drained (vmcnt0 before barrier)
            if (tid == 0) {
                unsigned int old = __hip_atomic_fetch_add(&cnt[p], 1u, __ATOMIC_ACQ_REL,
                                                          __HIP_MEMORY_SCOPE_AGENT);
                *wf = (old == 1);
            }
            __syncthreads();
            if (*wf) {
                const float* O0 = Opart + (size_t)p * 2 * 4096;
                const float* O1 = O0 + 4096;
                const float* L0 = Lpart + (size_t)p * 2 * 64;
                const float* L1 = L0 + 64;
                const int q  = tid >> 2;            // 0..63
                const int d0 = (tid & 3) * 16;
                const float inv = 1.0f / (L0[q] + L1[q]);
                const int t = qb + q;
                bf16_t* Ob = &O[(((size_t)(b_*TT + t))*HEADS + h)*HD + d0];
#pragma unroll
                for (int j = 0; j < 16; j += 4) {
                    f32x4 a = *reinterpret_cast<const f32x4*>(&O0[(size_t)q*64 + d0 + j]);
                    f32x4 b = *reinterpret_cast<const f32x4*>(&O1[(size_t)q*64 + d0 + j]);
                    bf16x4 o4;
#pragma unroll
                    for (int rr = 0; rr < 4; rr++) o4[rr] = (bf16_t)((a[rr] + b[rr]) * inv);
                    *reinterpret_cast<bf16x4*>(&Ob[j]) = o4;
                }
            }
        }
    }
}

// ---------------- launch ----------------
extern "C" void kernel_launch(void* const* d_in, const int* in_sizes, int n_in,
                              void* d_out, int out_size, void* d_ws, size_t ws_size,
                              hipStream_t stream) {
    const float* x  = (const float*)d_in[0];
    const float* Wq = (const float*)d_in[1];
    const float* Wk = (const float*)d_in[2];
    const float* Wv = (const float*)d_in[3];
    const float* Wo = (const float*)d_in[4];
    float* out = (float*)d_out;

    // workspace layout (bf16 elements), contiguous, 48 MB + 132 KB
    bf16_t* Xb  = (bf16_t*)d_ws;                       // 4M
    bf16_t* Wqb = Xb  + (size_t)MROWS * D_MODEL;       // 3M (Wq|Wk|Wv)
    bf16_t* Wob = Wqb + (size_t)3 * D_MODEL * D_MODEL; // 1M
    bf16_t* Qw  = Wob + (size_t)D_MODEL * D_MODEL;     // 4M  [B,H,T,D], pre-scaled
    bf16_t* Kw  = Qw  + (size_t)MROWS * D_MODEL;       // 4M  [B,H,T,D]
    bf16_t* Vt  = Kw  + (size_t)MROWS * D_MODEL;       // 4M  [B,H,D,T]
    bf16_t* Ow  = Vt  + (size_t)MROWS * D_MODEL;       // 4M  V-raw, then attn out [B,T,H,D]
    // split-merge scratch: Opart aliases Xb (dead during attn); cnt/Lpart at +48MB
    float*        Opart = (float*)Xb;                  // 256 pairs x 2 x 4096 f32 = 8 MiB
    unsigned int* cnt   = (unsigned int*)((char*)d_ws + (size_t)48*1024*1024);  // 1 KiB
    float*        Lpart = (float*)((char*)d_ws + (size_t)48*1024*1024 + 1024);  // 128 KiB

    // 1) convert all inputs to bf16 (+ zero the 256 split-merge counters)
    cvt_all_kernel<<<(MROWS*D_MODEL + 4*D_MODEL*D_MODEL) / 4 / 256, 256, 0, stream>>>(
        x, Wq, Wk, Wv, Wo, Xb, cnt);

    // 2) fused QKV projection (V-raw lands in the Ow slot, coalesced)
    dim3 gqkv(3 * D_MODEL / 128, MROWS / 128);
    gemm_bt<0,128><<<gqkv, 256, 0, stream>>>(Xb, Wqb, Qw, MROWS, 3 * D_MODEL, D_MODEL);

    // 3) V transpose -> [B,H,D,T]
    dim3 gt(TT / 64, BB * HEADS);
    transpose_v<<<gt, 256, 0, stream>>>(Ow, Vt);

    // 4) flash attention; 1024 blocks = 4/CU (overwrites Ow with [B,T,H,D] out)
    attn_kernel<<<dim3(1024), 256, 0, stream>>>(Qw, Kw, Vt, Ow, Opart, Lpart, cnt);

    // 5) output projection -> fp32 d_out (64-col tiles: 512 blocks = 2/CU)
    dim3 go(D_MODEL / 64, MROWS / 128);
    gemm_bt<2,64><<<go, 256, 0, stream>>>(Ow, Wob, out, MROWS, D_MODEL, D_MODEL);
}

// Round 7
// 183.726 us; speedup vs baseline: 1.2353x; 1.1149x over previous
//
#include <hip/hip_runtime.h>
#include <hip/hip_bf16.h>

// ---- types ----
typedef __bf16 bf16_t;
typedef __bf16 bf16x2 __attribute__((ext_vector_type(2)));
typedef __bf16 bf16x4 __attribute__((ext_vector_type(4)));
typedef __bf16 bf16x8 __attribute__((ext_vector_type(8)));
typedef float  f32x4  __attribute__((ext_vector_type(4)));
typedef int    i32x2  __attribute__((ext_vector_type(2)));

#define D_MODEL 1024
#define HEADS   16
#define HD      64
#define BB      2
#define TT      2048
#define MROWS   (BB*TT)   // 4096

#define GLDS16(g, l) __builtin_amdgcn_global_load_lds( \
    (const __attribute__((address_space(1))) void*)(g), \
    (__attribute__((address_space(3))) void*)(l), 16, 0, 0)

static __device__ __forceinline__ int pack_bf16(float a, float b) {
    bf16x2 t; t[0] = (bf16_t)a; t[1] = (bf16_t)b;
    return __builtin_bit_cast(int, t);
}

// ---------------- fused fp32 -> bf16 convert ----------------
__global__ __launch_bounds__(256) void cvt_all_kernel(const float* __restrict__ x,
                                                      const float* __restrict__ wq,
                                                      const float* __restrict__ wk,
                                                      const float* __restrict__ wv,
                                                      const float* __restrict__ wo,
                                                      bf16_t* __restrict__ dst) {
    const int i = blockIdx.x * 256 + threadIdx.x;   // vec4 index, total 2097152
    const float* src;
    int s;
    if (i < 1048576) { src = x; s = i; }
    else {
        int j = i - 1048576;
        int w = j >> 18;          // 262144 vec4 per weight
        s = j & 262143;
        src = (w == 0) ? wq : (w == 1) ? wk : (w == 2) ? wv : wo;
    }
    float4 v = reinterpret_cast<const float4*>(src)[s];
    bf16x4 o;
    o[0] = (bf16_t)v.x; o[1] = (bf16_t)v.y; o[2] = (bf16_t)v.z; o[3] = (bf16_t)v.w;
    reinterpret_cast<bf16x4*>(dst)[i] = o;
}

// ---------------- bf16 GEMM: C[M,N] = A[M,K] * B[N,K]^T ----------------
// BN = 128 or 64 (N-tile). M-tile fixed 128.
// MODE 0: fused QKV scatter (N=3072) -> [B,H,T,D] each; Q at Cout+0 (pre-scaled
//         by 0.125*log2e in fp32 before bf16 rounding), K at +4M, V at +12M
//         elements (the Ow slot, later transposed to Vt).
// MODE 2: fp32 row-major [M,N] (final output)
template<int MODE, int BN>
__global__ __launch_bounds__(256) void gemm_bt(const bf16_t* __restrict__ A,
                                               const bf16_t* __restrict__ Bw,
                                               void* __restrict__ Cout,
                                               int M, int N, int K) {
    constexpr int NI = BN / 32;     // n-tiles of 16 per wave
    __shared__ __align__(16) bf16_t As[128*32];
    __shared__ __align__(16) bf16_t Bs[BN*32];
    const int tid   = threadIdx.x;
    const int lane  = tid & 63;
    const int wave  = tid >> 6;
    const int col16 = lane & 15;
    const int quad  = lane >> 4;
    const int wrow  = (wave & 1) * 64;
    const int wcol  = (wave >> 1) * (BN / 2);
    const int bm    = blockIdx.y * 128;
    const int bn    = blockIdx.x * BN;

    const int lr = tid >> 2;        // 0..63
    const int lc = (tid & 3) * 8;   // 0,8,16,24

    const bf16_t* agp = &A [(size_t)(bm + lr)*K + lc];
    const bf16_t* bgp = &Bw[(size_t)(bn + lr)*K + lc];
    const size_t half = (size_t)64 * K;
    bf16_t* as_lo = &As[wave*512];
    bf16_t* as_hi = &As[2048 + wave*512];
    bf16_t* bs_lo = &Bs[wave*512];
    bf16_t* bs_hi = &Bs[2048 + wave*512];   // only used when BN==128

    f32x4 acc[4][NI];
#pragma unroll
    for (int i = 0; i < 4; i++)
#pragma unroll
        for (int j = 0; j < NI; j++) acc[i][j] = (f32x4){0.f, 0.f, 0.f, 0.f};

    for (int k0 = 0; k0 < K; k0 += 32) {
        GLDS16(agp + k0,        as_lo);
        GLDS16(agp + half + k0, as_hi);
        GLDS16(bgp + k0,        bs_lo);
        if (BN == 128) GLDS16(bgp + half + k0, bs_hi);
        __syncthreads();

        bf16x8 af[4], bfr[NI];
#pragma unroll
        for (int mi = 0; mi < 4; mi++)
            af[mi] = *reinterpret_cast<const bf16x8*>(&As[(wrow + mi*16 + col16)*32 + quad*8]);
#pragma unroll
        for (int ni = 0; ni < NI; ni++)
            bfr[ni] = *reinterpret_cast<const bf16x8*>(&Bs[(wcol + ni*16 + col16)*32 + quad*8]);
#pragma unroll
        for (int mi = 0; mi < 4; mi++)
#pragma unroll
            for (int ni = 0; ni < NI; ni++)
                acc[mi][ni] = __builtin_amdgcn_mfma_f32_16x16x32_bf16(af[mi], bfr[ni], acc[mi][ni], 0, 0, 0);
        __syncthreads();
    }

    // epilogue: C/D layout col=lane&15, row=quad*4+reg
#pragma unroll
    for (int mi = 0; mi < 4; mi++) {
#pragma unroll
        for (int r = 0; r < 4; r++) {
            const int gm = bm + wrow + mi*16 + quad*4 + r;
            const int t  = gm & (TT - 1);
            const int b  = gm >> 11;          // TT = 2048
#pragma unroll
            for (int ni = 0; ni < NI; ni++) {
                const int gn = bn + wcol + ni*16 + col16;
                float v = acc[mi][ni][r];
                if (MODE == 2) {
                    reinterpret_cast<float*>(Cout)[(size_t)gm * N + gn] = v;
                } else {
                    const int which = gn >> 10;       // 0=Q 1=K 2=V
                    if (which == 0) v *= 0.18033688f; // 0.125 * log2(e), fp32 pre-rounding
                    const int n = gn & 1023;
                    const int h = n >> 6, d = n & 63;
                    const size_t off = (size_t)(which == 2 ? 3 : which) * MROWS * D_MODEL;
                    bf16_t* base = reinterpret_cast<bf16_t*>(Cout) + off;
                    base[(((size_t)(b*HEADS + h))*TT + t)*HD + d] = (bf16_t)v;
                }
            }
        }
    }
}

// ---------------- V transpose: [B,H,T,D] -> [B,H,D,T] ----------------
__global__ __launch_bounds__(256) void transpose_v(const bf16_t* __restrict__ V,
                                                   bf16_t* __restrict__ Vt) {
    __shared__ bf16_t tile[64][72];
    const int tid = threadIdx.x;
    const int bh = blockIdx.y;
    const int t0 = blockIdx.x * 64;
    const bf16_t* src = V + ((size_t)bh * TT + t0) * HD;
#pragma unroll
    for (int i = 0; i < 2; i++) {
        const int r = i*32 + (tid >> 3), c = (tid & 7) * 8;
        *reinterpret_cast<bf16x8*>(&tile[r][c]) =
            *reinterpret_cast<const bf16x8*>(&src[(size_t)r * HD + c]);
    }
    __syncthreads();
    bf16_t* dst = Vt + (size_t)bh * HD * TT + t0;
#pragma unroll
    for (int i = 0; i < 2; i++) {
        const int d = i*32 + (tid >> 3), tc = (tid & 7) * 8;
        bf16x8 o;
#pragma unroll
        for (int j = 0; j < 8; j++) o[j] = tile[tc + j][d];
        *reinterpret_cast<bf16x8*>(&dst[(size_t)d * TT + tc]) = o;
    }
}

// ---------------- flash attention: 4 waves/block, 64 q-rows, 64-key tiles ----
// R11 = R8 (best verified: attn 43.1us) + s_setprio around the pure-MFMA
// clusters (T5: attn-regime +4-7%; independent blocks at different phases ->
// CU scheduler favors MFMA-entering waves over memory/VALU-issuing peers).
// R9/R10 split-schedule experiments REVERTED: both regressed (split/merge
// data path + remap overhead exceeded the 32->24 round chain reduction).
// Waves = (kw key-half, qw query-half): 32q x 32k sub-tile per wave; partials
// over disjoint key halves exactly additive (no-max softmax) -> one LDS merge.
// PV B-frag redistribution via permlane{32,16}_swap builtins (R8, hazard-safe).
// Balanced packing {31-g, g, 15-g, 16+g}: CU-set of 4 sums to 66 rounds.
// S^T formulation: S^T = K.Q^T; Q pre-scaled by 0.125*log2e. Vt: [B,H,D,T].
__global__ __launch_bounds__(256, 4) void attn_kernel(const bf16_t* __restrict__ Q,
                                                      const bf16_t* __restrict__ Kk,
                                                      const bf16_t* __restrict__ Vt,
                                                      bf16_t* __restrict__ O) {
    __shared__ __align__(16) bf16_t Ks[2][64*64];   // [key][d-chunks], XOR-swizzled
    __shared__ __align__(16) bf16_t Vs[2][64*64];   // [d][key-chunks], XOR-swizzled

    const int tid   = threadIdx.x;
    const int lane  = tid & 63;
    const int wave  = tid >> 6;
    const int col16 = lane & 15;
    const int quad  = lane >> 4;
    const int kw    = wave & 1;    // key-half this wave owns (keys kw*32..kw*32+31)
    const int qw    = wave >> 1;   // query-half this wave owns (rows qb+qw*32..+31)

    const int bx = blockIdx.x;
    const int r_ = bx >> 8, s_ = bx & 255;
    const int bh = s_ & 31;
    const int g  = s_ >> 5;
    // balanced partition: {31-g, g, 15-g, 16+g} -> uniform 66 rounds per CU-set
    const int qt = (r_ == 0) ? (31 - g)
                 : (r_ == 1) ? g
                 : (r_ == 2) ? (15 - g)
                             : (16 + g);
    const int qb    = qt * 64;
    const int qbase = qb + qw * 32;
    const int nkt   = qt + 1;

    const bf16_t* Qb = Q  + (size_t)bh * TT * HD;
    const bf16_t* Kb = Kk + (size_t)bh * TT * HD;
    const bf16_t* Vb = Vt + (size_t)bh * HD * TT;

    // Q fragments (B-operand layout B[k=d][n=q]) for both 16-row query groups
    bf16x8 qf[2][2];
#pragma unroll
    for (int qg = 0; qg < 2; qg++)
#pragma unroll
        for (int h = 0; h < 2; h++)
            qf[qg][h] = *reinterpret_cast<const bf16x8*>(
                &Qb[(size_t)(qbase + qg*16 + col16)*HD + h*32 + quad*8]);

    // staging geometry: each shot = 256 threads x 16B = 4KB = 32 rows x 64 cols.
    // LDS[row*64 + ch*8 + i] = src[row][(ch ^ (row&7))*8 + i]  (XOR swizzle).
    const int srow = (tid >> 3) & 31;
    const int sg   = ((lane & 7) ^ (srow & 7)) * 8;

    auto stage = [&](int kt, int buf) {
        const int s0 = kt * 64;
        GLDS16(&Kb[(size_t)(s0 + srow)*HD + sg],        &Ks[buf][wave*512]);
        GLDS16(&Kb[(size_t)(s0 + srow + 32)*HD + sg],   &Ks[buf][2048 + wave*512]);
        GLDS16(&Vb[(size_t)srow*TT + s0 + sg],          &Vs[buf][wave*512]);
        GLDS16(&Vb[(size_t)(srow + 32)*TT + s0 + sg],   &Vs[buf][2048 + wave*512]);
    };

    // out^T partial over this wave's key half:
    // acc[c][qg][r] = O^T[d = c*16+quad*4+r][q = qg*16+col16]
    f32x4 acc[4][2];
#pragma unroll
    for (int i = 0; i < 4; i++)
#pragma unroll
        for (int j = 0; j < 2; j++) acc[i][j] = (f32x4){0.f,0.f,0.f,0.f};
    float lsum[2] = {0.f, 0.f};     // partial softmax denoms (this key half)

    const int x7 = col16 & 7;

    stage(0, 0);
    __syncthreads();

    for (int kt = 0; kt < nkt; kt++) {
        const int buf = kt & 1;
        if (kt + 1 < nkt) stage(kt + 1, buf ^ 1);   // async prefetch, drained by end barrier
        const int s0 = kt * 64;
        const bool diag = (kt == nkt - 1);

        // ---- S^T = K Q^T on this wave's 32 keys x 32 queries ----
        bf16x8 kf0[2], kf1[2];
#pragma unroll
        for (int c = 0; c < 2; c++) {
            // K A-frag: A[m=key][k=d]: lane holds K[s0+kw*32+c*16+col16][d-chunk]
            kf0[c] = *reinterpret_cast<const bf16x8*>(
                &Ks[buf][(kw*32 + c*16 + col16)*64 + ((0*4 + quad) ^ x7)*8]);
            kf1[c] = *reinterpret_cast<const bf16x8*>(
                &Ks[buf][(kw*32 + c*16 + col16)*64 + ((1*4 + quad) ^ x7)*8]);
        }

        int pk[2][2][2];   // pk[c][qg][x]: keys kw*32+c*16+quad*4+{2x,2x+1}, query qg*16+col16
#pragma unroll
        for (int c = 0; c < 2; c++) {
#pragma unroll
            for (int qg = 0; qg < 2; qg++) {
                __builtin_amdgcn_s_setprio(1);
                f32x4 sv = __builtin_amdgcn_mfma_f32_16x16x32_bf16(kf0[c], qf[qg][0], (f32x4){0.f,0.f,0.f,0.f}, 0, 0, 0);
                sv       = __builtin_amdgcn_mfma_f32_16x16x32_bf16(kf1[c], qf[qg][1], sv, 0, 0, 0);
                __builtin_amdgcn_s_setprio(0);

                float pr[4];
#pragma unroll
                for (int r = 0; r < 4; r++) pr[r] = exp2f(sv[r]);   // scale baked into Q
                if (diag) {   // causal mask, block-uniform branch
#pragma unroll
                    for (int r = 0; r < 4; r++)
                        if (s0 + kw*32 + c*16 + quad*4 + r > qbase + qg*16 + col16) pr[r] = 0.f;
                }
                lsum[qg] += (pr[0] + pr[1]) + (pr[2] + pr[3]);
                pk[c][qg][0] = pack_bf16(pr[0], pr[1]);
                pk[c][qg][1] = pack_bf16(pr[2], pr[3]);
            }
        }

        // ---- PV: out^T += V^T P^T over this wave's 32-key chunk ----
        bf16x8 pf[2];
#pragma unroll
        for (int qg = 0; qg < 2; qg++) {
#if __has_builtin(__builtin_amdgcn_permlane32_swap)
            i32x2 u0 = __builtin_amdgcn_permlane32_swap(pk[0][qg][0], pk[1][qg][0], false, false);
            i32x2 v0 = __builtin_amdgcn_permlane16_swap(u0[0], u0[1], false, false);
            i32x2 u1 = __builtin_amdgcn_permlane32_swap(pk[0][qg][1], pk[1][qg][1], false, false);
            i32x2 v1 = __builtin_amdgcn_permlane16_swap(u1[0], u1[1], false, false);
            int4 bi = { v0[0], v1[0], v0[1], v1[1] };   // slots 0,1,2,3
#else
            const int a1 = ((quad & 1) * 32 + col16) * 4;
            const int a2 = a1 + 64;
            const bool hi = quad >= 2;
            int b0l = __builtin_amdgcn_ds_bpermute(a1, pk[0][qg][0]);
            int b0h = __builtin_amdgcn_ds_bpermute(a1, pk[1][qg][0]);
            int b1l = __builtin_amdgcn_ds_bpermute(a1, pk[0][qg][1]);
            int b1h = __builtin_amdgcn_ds_bpermute(a1, pk[1][qg][1]);
            int b2l = __builtin_amdgcn_ds_bpermute(a2, pk[0][qg][0]);
            int b2h = __builtin_amdgcn_ds_bpermute(a2, pk[1][qg][0]);
            int b3l = __builtin_amdgcn_ds_bpermute(a2, pk[0][qg][1]);
            int b3h = __builtin_amdgcn_ds_bpermute(a2, pk[1][qg][1]);
            int4 bi = { hi ? b0h : b0l, hi ? b1h : b1l, hi ? b2h : b2l, hi ? b3h : b3l };
#endif
            pf[qg] = __builtin_bit_cast(bf16x8, bi);
        }
        __builtin_amdgcn_s_setprio(1);
#pragma unroll
        for (int c = 0; c < 4; c++) {
            // V^T A-frag: A[m=d][k=key]: lane holds V^T[c*16+col16][s0+kw*32+quad*8+j]
            bf16x8 vf = *reinterpret_cast<const bf16x8*>(
                &Vs[buf][(c*16 + col16)*64 + ((kw*4 + quad) ^ x7)*8]);
            acc[c][0] = __builtin_amdgcn_mfma_f32_16x16x32_bf16(vf, pf[0], acc[c][0], 0, 0, 0);
            acc[c][1] = __builtin_amdgcn_mfma_f32_16x16x32_bf16(vf, pf[1], acc[c][1], 0, 0, 0);
        }
        __builtin_amdgcn_s_setprio(0);
        __syncthreads();   // drains prefetch (vmcnt0) + protects LDS buffers
    }

    // partial denoms: sum across quads (same query col16) within the wave
#pragma unroll
    for (int qg = 0; qg < 2; qg++) {
        lsum[qg] += __shfl_xor(lsum[qg], 16);
        lsum[qg] += __shfl_xor(lsum[qg], 32);
    }

    // ---- cross-kw merge (partials are additive: no-max softmax) ----
    // kw=1 waves park their partials in LDS (reusing the K/V buffers, which
    // the final loop barrier has released); qw selects the buffer so the two
    // kw=1 waves never collide. Layout: M[32 q][68 d] f32 (pad 68 vs 64).
    float* Mq = qw ? reinterpret_cast<float*>(&Vs[0][0])
                   : reinterpret_cast<float*>(&Ks[0][0]);
    float* LS = reinterpret_cast<float*>(&Vs[0][0]) + 32*68;   // 64 denom slots

    if (kw == 1) {
#pragma unroll
        for (int c = 0; c < 4; c++)
#pragma unroll
            for (int qg = 0; qg < 2; qg++)
                *reinterpret_cast<f32x4*>(&Mq[(qg*16 + col16)*68 + c*16 + quad*4]) = acc[c][qg];
        if (lane < 16) {
            LS[qw*32 + lane]      = lsum[0];
            LS[qw*32 + 16 + lane] = lsum[1];
        }
    }
    __syncthreads();

    if (kw == 0) {
        const int b_ = bh >> 4, h = bh & 15;
#pragma unroll
        for (int qg = 0; qg < 2; qg++) {
            const float l   = lsum[qg] + LS[qw*32 + qg*16 + col16];
            const float inv = 1.0f / l;
            const int t = qbase + qg*16 + col16;
            bf16_t* Ob = &O[(((size_t)(b_*TT + t))*HEADS + h)*HD + quad*4];
#pragma unroll
            for (int c = 0; c < 4; c++) {
                f32x4 m = *reinterpret_cast<const f32x4*>(&Mq[(qg*16 + col16)*68 + c*16 + quad*4]);
                bf16x4 o4;
#pragma unroll
                for (int r = 0; r < 4; r++) o4[r] = (bf16_t)((acc[c][qg][r] + m[r]) * inv);
                *reinterpret_cast<bf16x4*>(&Ob[c*16]) = o4;
            }
        }
    }
}

// ---------------- launch ----------------
extern "C" void kernel_launch(void* const* d_in, const int* in_sizes, int n_in,
                              void* d_out, int out_size, void* d_ws, size_t ws_size,
                              hipStream_t stream) {
    const float* x  = (const float*)d_in[0];
    const float* Wq = (const float*)d_in[1];
    const float* Wk = (const float*)d_in[2];
    const float* Wv = (const float*)d_in[3];
    const float* Wo = (const float*)d_in[4];
    float* out = (float*)d_out;

    // workspace layout (bf16 elements), contiguous, 48 MB total
    bf16_t* Xb  = (bf16_t*)d_ws;                       // 4M
    bf16_t* Wqb = Xb  + (size_t)MROWS * D_MODEL;       // 3M (Wq|Wk|Wv)
    bf16_t* Wob = Wqb + (size_t)3 * D_MODEL * D_MODEL; // 1M
    bf16_t* Qw  = Wob + (size_t)D_MODEL * D_MODEL;     // 4M  [B,H,T,D], pre-scaled
    bf16_t* Kw  = Qw  + (size_t)MROWS * D_MODEL;       // 4M  [B,H,T,D]
    bf16_t* Vt  = Kw  + (size_t)MROWS * D_MODEL;       // 4M  [B,H,D,T]
    bf16_t* Ow  = Vt  + (size_t)MROWS * D_MODEL;       // 4M  V-raw, then attn out [B,T,H,D]

    // 1) convert all inputs to bf16
    cvt_all_kernel<<<(MROWS*D_MODEL + 4*D_MODEL*D_MODEL) / 4 / 256, 256, 0, stream>>>(
        x, Wq, Wk, Wv, Wo, Xb);

    // 2) fused QKV projection (V-raw lands in the Ow slot, coalesced)
    dim3 gqkv(3 * D_MODEL / 128, MROWS / 128);
    gemm_bt<0,128><<<gqkv, 256, 0, stream>>>(Xb, Wqb, Qw, MROWS, 3 * D_MODEL, D_MODEL);

    // 3) V transpose -> [B,H,D,T]
    dim3 gt(TT / 64, BB * HEADS);
    transpose_v<<<gt, 256, 0, stream>>>(Ow, Vt);

    // 4) flash attention (overwrites Ow with attention output); 1024 blocks
    attn_kernel<<<dim3(1024), 256, 0, stream>>>(Qw, Kw, Vt, Ow);

    // 5) output projection -> fp32 d_out (64-col tiles: 512 blocks = 2/CU)
    dim3 go(D_MODEL / 64, MROWS / 128);
    gemm_bt<2,64><<<go, 256, 0, stream>>>(Ow, Wob, out, MROWS, D_MODEL, D_MODEL);
}

// Round 10
// 172.755 us; speedup vs baseline: 1.3137x; 1.0635x over previous
//
#include <hip/hip_runtime.h>
#include <hip/hip_bf16.h>

// ---- types ----
typedef __bf16 bf16_t;
typedef __bf16 bf16x2 __attribute__((ext_vector_type(2)));
typedef __bf16 bf16x4 __attribute__((ext_vector_type(4)));
typedef __bf16 bf16x8 __attribute__((ext_vector_type(8)));
typedef float  f32x4  __attribute__((ext_vector_type(4)));
typedef int    i32x2  __attribute__((ext_vector_type(2)));

#define D_MODEL 1024
#define HEADS   16
#define HD      64
#define BB      2
#define TT      2048
#define MROWS   (BB*TT)   // 4096

#define GLDS16(g, l) __builtin_amdgcn_global_load_lds( \
    (const __attribute__((address_space(1))) void*)(g), \
    (__attribute__((address_space(3))) void*)(l), 16, 0, 0)

static __device__ __forceinline__ int pack_bf16(float a, float b) {
    bf16x2 t; t[0] = (bf16_t)a; t[1] = (bf16_t)b;
    return __builtin_bit_cast(int, t);
}

// ---------------- fused fp32 -> bf16 convert ----------------
__global__ __launch_bounds__(256) void cvt_all_kernel(const float* __restrict__ x,
                                                      const float* __restrict__ wq,
                                                      const float* __restrict__ wk,
                                                      const float* __restrict__ wv,
                                                      const float* __restrict__ wo,
                                                      bf16_t* __restrict__ dst) {
    const int i = blockIdx.x * 256 + threadIdx.x;   // vec4 index, total 2097152
    const float* src;
    int s;
    if (i < 1048576) { src = x; s = i; }
    else {
        int j = i - 1048576;
        int w = j >> 18;          // 262144 vec4 per weight
        s = j & 262143;
        src = (w == 0) ? wq : (w == 1) ? wk : (w == 2) ? wv : wo;
    }
    float4 v = reinterpret_cast<const float4*>(src)[s];
    bf16x4 o;
    o[0] = (bf16_t)v.x; o[1] = (bf16_t)v.y; o[2] = (bf16_t)v.z; o[3] = (bf16_t)v.w;
    reinterpret_cast<bf16x4*>(dst)[i] = o;
}

// ---------------- bf16 GEMM: C[M,N] = A[M,K] * B[N,K]^T ----------------
// R12 (3rd submit; rounds 8/9 failed on sick nodes — push times 200-600s vs
// ~0s healthy; audit found no OOB/hang: staging is byte-identical to the attn
// kernel's 9-round-verified pattern. If this crashes again, revert to R11.)
// BK 32->64 (halves barrier/drain instances; 32 MFMA per K-step per wave) +
// XOR swizzle: LDS rows are 128B = 8 chunks of 16B; staging pre-swizzles the
// GLOBAL source chunk (chunk ^ (row&7), linear LDS dest — GLDS-legal) and
// reads use ((h*4+quad) ^ (row&7)).
// Old BK=32 layout had row-stride 64B -> bank starts {0,16} only -> 8-way
// conflict on every ds_read_b128 (SQ_LDS_BANK_CONFLICT 3.1M, 2.94x LDS cost);
// swizzled starts cover all 8 16B-slots per 8 rows -> 2-way = free.
// BN = 128 or 64 (N-tile). M-tile fixed 128.
// MODE 0: fused QKV scatter (N=3072) -> [B,H,T,D] each; Q at Cout+0 (pre-scaled
//         by 0.125*log2e in fp32 before bf16 rounding), K at +4M, V at +12M
//         elements (the Ow slot, later transposed to Vt).
// MODE 2: fp32 row-major [M,N] (final output)
template<int MODE, int BN>
__global__ __launch_bounds__(256, 3) void gemm_bt(const bf16_t* __restrict__ A,
                                                  const bf16_t* __restrict__ Bw,
                                                  void* __restrict__ Cout,
                                                  int M, int N, int K) {
    constexpr int NI = BN / 32;     // n-tiles of 16 per wave
    __shared__ __align__(16) bf16_t As[128*64];
    __shared__ __align__(16) bf16_t Bs[BN*64];
    const int tid   = threadIdx.x;
    const int lane  = tid & 63;
    const int wave  = tid >> 6;
    const int col16 = lane & 15;
    const int quad  = lane >> 4;
    const int wrow  = (wave & 1) * 64;
    const int wcol  = (wave >> 1) * (BN / 2);
    const int bm    = blockIdx.y * 128;
    const int bn    = blockIdx.x * BN;
    const int x7    = col16 & 7;    // row&7 for all fragment rows (wrow,mi*16 = 0 mod 8)

    // staging: shot = 256 threads x 16B = 4KB = 32 rows x 64 cols (bf16).
    // thread -> row lr = tid>>3 (0..31), LDS chunk slot tid&7; global chunk
    // fetched = (tid&7) ^ (lr&7)  => LDS slot c of row r holds global chunk
    // c ^ (r&7); reads invert with the same XOR.
    const int lr = tid >> 3;
    const int lc = ((tid & 7) ^ (lr & 7)) * 8;

    const bf16_t* agp = &A [(size_t)(bm + lr)*K + lc];
    const bf16_t* bgp = &Bw[(size_t)(bn + lr)*K + lc];

    f32x4 acc[4][NI];
#pragma unroll
    for (int i = 0; i < 4; i++)
#pragma unroll
        for (int j = 0; j < NI; j++) acc[i][j] = (f32x4){0.f, 0.f, 0.f, 0.f};

    for (int k0 = 0; k0 < K; k0 += 64) {
#pragma unroll
        for (int s = 0; s < 4; s++)             // A: 128 rows = 4 shots
            GLDS16(agp + k0 + (size_t)s*32*K, &As[s*2048 + wave*512]);
#pragma unroll
        for (int s = 0; s < BN/32; s++)         // B: BN rows
            GLDS16(bgp + k0 + (size_t)s*32*K, &Bs[s*2048 + wave*512]);
        __syncthreads();

        bf16x8 af[4][2], bfr[NI][2];
#pragma unroll
        for (int mi = 0; mi < 4; mi++)
#pragma unroll
            for (int h = 0; h < 2; h++)
                af[mi][h] = *reinterpret_cast<const bf16x8*>(
                    &As[(wrow + mi*16 + col16)*64 + ((h*4 + quad) ^ x7)*8]);
#pragma unroll
        for (int ni = 0; ni < NI; ni++)
#pragma unroll
            for (int h = 0; h < 2; h++)
                bfr[ni][h] = *reinterpret_cast<const bf16x8*>(
                    &Bs[(wcol + ni*16 + col16)*64 + ((h*4 + quad) ^ x7)*8]);
#pragma unroll
        for (int mi = 0; mi < 4; mi++)
#pragma unroll
            for (int ni = 0; ni < NI; ni++) {
                acc[mi][ni] = __builtin_amdgcn_mfma_f32_16x16x32_bf16(af[mi][0], bfr[ni][0], acc[mi][ni], 0, 0, 0);
                acc[mi][ni] = __builtin_amdgcn_mfma_f32_16x16x32_bf16(af[mi][1], bfr[ni][1], acc[mi][ni], 0, 0, 0);
            }
        __syncthreads();
    }

    // epilogue: C/D layout col=lane&15, row=quad*4+reg
#pragma unroll
    for (int mi = 0; mi < 4; mi++) {
#pragma unroll
        for (int r = 0; r < 4; r++) {
            const int gm = bm + wrow + mi*16 + quad*4 + r;
            const int t  = gm & (TT - 1);
            const int b  = gm >> 11;          // TT = 2048
#pragma unroll
            for (int ni = 0; ni < NI; ni++) {
                const int gn = bn + wcol + ni*16 + col16;
                float v = acc[mi][ni][r];
                if (MODE == 2) {
                    reinterpret_cast<float*>(Cout)[(size_t)gm * N + gn] = v;
                } else {
                    const int which = gn >> 10;       // 0=Q 1=K 2=V
                    if (which == 0) v *= 0.18033688f; // 0.125 * log2(e), fp32 pre-rounding
                    const int n = gn & 1023;
                    const int h = n >> 6, d = n & 63;
                    const size_t off = (size_t)(which == 2 ? 3 : which) * MROWS * D_MODEL;
                    bf16_t* base = reinterpret_cast<bf16_t*>(Cout) + off;
                    base[(((size_t)(b*HEADS + h))*TT + t)*HD + d] = (bf16_t)v;
                }
            }
        }
    }
}

// ---------------- V transpose: [B,H,T,D] -> [B,H,D,T] ----------------
__global__ __launch_bounds__(256) void transpose_v(const bf16_t* __restrict__ V,
                                                   bf16_t* __restrict__ Vt) {
    __shared__ bf16_t tile[64][72];
    const int tid = threadIdx.x;
    const int bh = blockIdx.y;
    const int t0 = blockIdx.x * 64;
    const bf16_t* src = V + ((size_t)bh * TT + t0) * HD;
#pragma unroll
    for (int i = 0; i < 2; i++) {
        const int r = i*32 + (tid >> 3), c = (tid & 7) * 8;
        *reinterpret_cast<bf16x8*>(&tile[r][c]) =
            *reinterpret_cast<const bf16x8*>(&src[(size_t)r * HD + c]);
    }
    __syncthreads();
    bf16_t* dst = Vt + (size_t)bh * HD * TT + t0;
#pragma unroll
    for (int i = 0; i < 2; i++) {
        const int d = i*32 + (tid >> 3), tc = (tid & 7) * 8;
        bf16x8 o;
#pragma unroll
        for (int j = 0; j < 8; j++) o[j] = tile[tc + j][d];
        *reinterpret_cast<bf16x8*>(&dst[(size_t)d * TT + tc]) = o;
    }
}

// ---------------- flash attention: 4 waves/block, 64 q-rows, 64-key tiles ----
// R11 (unchanged, verified): R8 structure + s_setprio around pure-MFMA
// clusters (T5 attn-regime). Waves = (kw key-half, qw query-half): 32q x 32k
// sub-tile per wave; partials over disjoint key halves exactly additive
// (no-max softmax) -> one LDS merge. PV B-frag redistribution via
// permlane{32,16}_swap builtins. Balanced packing {31-g, g, 15-g, 16+g}:
// CU-set of 4 sums to 66 rounds.
// S^T formulation: S^T = K.Q^T; Q pre-scaled by 0.125*log2e. Vt: [B,H,D,T].
__global__ __launch_bounds__(256, 4) void attn_kernel(const bf16_t* __restrict__ Q,
                                                      const bf16_t* __restrict__ Kk,
                                                      const bf16_t* __restrict__ Vt,
                                                      bf16_t* __restrict__ O) {
    __shared__ __align__(16) bf16_t Ks[2][64*64];   // [key][d-chunks], XOR-swizzled
    __shared__ __align__(16) bf16_t Vs[2][64*64];   // [d][key-chunks], XOR-swizzled

    const int tid   = threadIdx.x;
    const int lane  = tid & 63;
    const int wave  = tid >> 6;
    const int col16 = lane & 15;
    const int quad  = lane >> 4;
    const int kw    = wave & 1;    // key-half this wave owns (keys kw*32..kw*32+31)
    const int qw    = wave >> 1;   // query-half this wave owns (rows qb+qw*32..+31)

    const int bx = blockIdx.x;
    const int r_ = bx >> 8, s_ = bx & 255;
    const int bh = s_ & 31;
    const int g  = s_ >> 5;
    // balanced partition: {31-g, g, 15-g, 16+g} -> uniform 66 rounds per CU-set
    const int qt = (r_ == 0) ? (31 - g)
                 : (r_ == 1) ? g
                 : (r_ == 2) ? (15 - g)
                             : (16 + g);
    const int qb    = qt * 64;
    const int qbase = qb + qw * 32;
    const int nkt   = qt + 1;

    const bf16_t* Qb = Q  + (size_t)bh * TT * HD;
    const bf16_t* Kb = Kk + (size_t)bh * TT * HD;
    const bf16_t* Vb = Vt + (size_t)bh * HD * TT;

    // Q fragments (B-operand layout B[k=d][n=q]) for both 16-row query groups
    bf16x8 qf[2][2];
#pragma unroll
    for (int qg = 0; qg < 2; qg++)
#pragma unroll
        for (int h = 0; h < 2; h++)
            qf[qg][h] = *reinterpret_cast<const bf16x8*>(
                &Qb[(size_t)(qbase + qg*16 + col16)*HD + h*32 + quad*8]);

    // staging geometry: each shot = 256 threads x 16B = 4KB = 32 rows x 64 cols.
    // LDS[row*64 + ch*8 + i] = src[row][(ch ^ (row&7))*8 + i]  (XOR swizzle).
    const int srow = (tid >> 3) & 31;
    const int sg   = ((lane & 7) ^ (srow & 7)) * 8;

    auto stage = [&](int kt, int buf) {
        const int s0 = kt * 64;
        GLDS16(&Kb[(size_t)(s0 + srow)*HD + sg],        &Ks[buf][wave*512]);
        GLDS16(&Kb[(size_t)(s0 + srow + 32)*HD + sg],   &Ks[buf][2048 + wave*512]);
        GLDS16(&Vb[(size_t)srow*TT + s0 + sg],          &Vs[buf][wave*512]);
        GLDS16(&Vb[(size_t)(srow + 32)*TT + s0 + sg],   &Vs[buf][2048 + wave*512]);
    };

    // out^T partial over this wave's key half:
    // acc[c][qg][r] = O^T[d = c*16+quad*4+r][q = qg*16+col16]
    f32x4 acc[4][2];
#pragma unroll
    for (int i = 0; i < 4; i++)
#pragma unroll
        for (int j = 0; j < 2; j++) acc[i][j] = (f32x4){0.f,0.f,0.f,0.f};
    float lsum[2] = {0.f, 0.f};     // partial softmax denoms (this key half)

    const int x7 = col16 & 7;

    stage(0, 0);
    __syncthreads();

    for (int kt = 0; kt < nkt; kt++) {
        const int buf = kt & 1;
        if (kt + 1 < nkt) stage(kt + 1, buf ^ 1);   // async prefetch, drained by end barrier
        const int s0 = kt * 64;
        const bool diag = (kt == nkt - 1);

        // ---- S^T = K Q^T on this wave's 32 keys x 32 queries ----
        bf16x8 kf0[2], kf1[2];
#pragma unroll
        for (int c = 0; c < 2; c++) {
            // K A-frag: A[m=key][k=d]: lane holds K[s0+kw*32+c*16+col16][d-chunk]
            kf0[c] = *reinterpret_cast<const bf16x8*>(
                &Ks[buf][(kw*32 + c*16 + col16)*64 + ((0*4 + quad) ^ x7)*8]);
            kf1[c] = *reinterpret_cast<const bf16x8*>(
                &Ks[buf][(kw*32 + c*16 + col16)*64 + ((1*4 + quad) ^ x7)*8]);
        }

        int pk[2][2][2];   // pk[c][qg][x]: keys kw*32+c*16+quad*4+{2x,2x+1}, query qg*16+col16
#pragma unroll
        for (int c = 0; c < 2; c++) {
#pragma unroll
            for (int qg = 0; qg < 2; qg++) {
                __builtin_amdgcn_s_setprio(1);
                f32x4 sv = __builtin_amdgcn_mfma_f32_16x16x32_bf16(kf0[c], qf[qg][0], (f32x4){0.f,0.f,0.f,0.f}, 0, 0, 0);
                sv       = __builtin_amdgcn_mfma_f32_16x16x32_bf16(kf1[c], qf[qg][1], sv, 0, 0, 0);
                __builtin_amdgcn_s_setprio(0);

                float pr[4];
#pragma unroll
                for (int r = 0; r < 4; r++) pr[r] = exp2f(sv[r]);   // scale baked into Q
                if (diag) {   // causal mask, block-uniform branch
#pragma unroll
                    for (int r = 0; r < 4; r++)
                        if (s0 + kw*32 + c*16 + quad*4 + r > qbase + qg*16 + col16) pr[r] = 0.f;
                }
                lsum[qg] += (pr[0] + pr[1]) + (pr[2] + pr[3]);
                pk[c][qg][0] = pack_bf16(pr[0], pr[1]);
                pk[c][qg][1] = pack_bf16(pr[2], pr[3]);
            }
        }

        // ---- PV: out^T += V^T P^T over this wave's 32-key chunk ----
        bf16x8 pf[2];
#pragma unroll
        for (int qg = 0; qg < 2; qg++) {
#if __has_builtin(__builtin_amdgcn_permlane32_swap)
            i32x2 u0 = __builtin_amdgcn_permlane32_swap(pk[0][qg][0], pk[1][qg][0], false, false);
            i32x2 v0 = __builtin_amdgcn_permlane16_swap(u0[0], u0[1], false, false);
            i32x2 u1 = __builtin_amdgcn_permlane32_swap(pk[0][qg][1], pk[1][qg][1], false, false);
            i32x2 v1 = __builtin_amdgcn_permlane16_swap(u1[0], u1[1], false, false);
            int4 bi = { v0[0], v1[0], v0[1], v1[1] };   // slots 0,1,2,3
#else
            const int a1 = ((quad & 1) * 32 + col16) * 4;
            const int a2 = a1 + 64;
            const bool hi = quad >= 2;
            int b0l = __builtin_amdgcn_ds_bpermute(a1, pk[0][qg][0]);
            int b0h = __builtin_amdgcn_ds_bpermute(a1, pk[1][qg][0]);
            int b1l = __builtin_amdgcn_ds_bpermute(a1, pk[0][qg][1]);
            int b1h = __builtin_amdgcn_ds_bpermute(a1, pk[1][qg][1]);
            int b2l = __builtin_amdgcn_ds_bpermute(a2, pk[0][qg][0]);
            int b2h = __builtin_amdgcn_ds_bpermute(a2, pk[1][qg][0]);
            int b3l = __builtin_amdgcn_ds_bpermute(a2, pk[0][qg][1]);
            int b3h = __builtin_amdgcn_ds_bpermute(a2, pk[1][qg][1]);
            int4 bi = { hi ? b0h : b0l, hi ? b1h : b1l, hi ? b2h : b2l, hi ? b3h : b3l };
#endif
            pf[qg] = __builtin_bit_cast(bf16x8, bi);
        }
        __builtin_amdgcn_s_setprio(1);
#pragma unroll
        for (int c = 0; c < 4; c++) {
            // V^T A-frag: A[m=d][k=key]: lane holds V^T[c*16+col16][s0+kw*32+quad*8+j]
            bf16x8 vf = *reinterpret_cast<const bf16x8*>(
                &Vs[buf][(c*16 + col16)*64 + ((kw*4 + quad) ^ x7)*8]);
            acc[c][0] = __builtin_amdgcn_mfma_f32_16x16x32_bf16(vf, pf[0], acc[c][0], 0, 0, 0);
            acc[c][1] = __builtin_amdgcn_mfma_f32_16x16x32_bf16(vf, pf[1], acc[c][1], 0, 0, 0);
        }
        __builtin_amdgcn_s_setprio(0);
        __syncthreads();   // drains prefetch (vmcnt0) + protects LDS buffers
    }

    // partial denoms: sum across quads (same query col16) within the wave
#pragma unroll
    for (int qg = 0; qg < 2; qg++) {
        lsum[qg] += __shfl_xor(lsum[qg], 16);
        lsum[qg] += __shfl_xor(lsum[qg], 32);
    }

    // ---- cross-kw merge (partials are additive: no-max softmax) ----
    // kw=1 waves park their partials in LDS (reusing the K/V buffers, which
    // the final loop barrier has released); qw selects the buffer so the two
    // kw=1 waves never collide. Layout: M[32 q][68 d] f32 (pad 68 vs 64).
    float* Mq = qw ? reinterpret_cast<float*>(&Vs[0][0])
                   : reinterpret_cast<float*>(&Ks[0][0]);
    float* LS = reinterpret_cast<float*>(&Vs[0][0]) + 32*68;   // 64 denom slots

    if (kw == 1) {
#pragma unroll
        for (int c = 0; c < 4; c++)
#pragma unroll
            for (int qg = 0; qg < 2; qg++)
                *reinterpret_cast<f32x4*>(&Mq[(qg*16 + col16)*68 + c*16 + quad*4]) = acc[c][qg];
        if (lane < 16) {
            LS[qw*32 + lane]      = lsum[0];
            LS[qw*32 + 16 + lane] = lsum[1];
        }
    }
    __syncthreads();

    if (kw == 0) {
        const int b_ = bh >> 4, h = bh & 15;
#pragma unroll
        for (int qg = 0; qg < 2; qg++) {
            const float l   = lsum[qg] + LS[qw*32 + qg*16 + col16];
            const float inv = 1.0f / l;
            const int t = qbase + qg*16 + col16;
            bf16_t* Ob = &O[(((size_t)(b_*TT + t))*HEADS + h)*HD + quad*4];
#pragma unroll
            for (int c = 0; c < 4; c++) {
                f32x4 m = *reinterpret_cast<const f32x4*>(&Mq[(qg*16 + col16)*68 + c*16 + quad*4]);
                bf16x4 o4;
#pragma unroll
                for (int r = 0; r < 4; r++) o4[r] = (bf16_t)((acc[c][qg][r] + m[r]) * inv);
                *reinterpret_cast<bf16x4*>(&Ob[c*16]) = o4;
            }
        }
    }
}

// ---------------- launch ----------------
extern "C" void kernel_launch(void* const* d_in, const int* in_sizes, int n_in,
                              void* d_out, int out_size, void* d_ws, size_t ws_size,
                              hipStream_t stream) {
    const float* x  = (const float*)d_in[0];
    const float* Wq = (const float*)d_in[1];
    const float* Wk = (const float*)d_in[2];
    const float* Wv = (const float*)d_in[3];
    const float* Wo = (const float*)d_in[4];
    float* out = (float*)d_out;

    // workspace layout (bf16 elements), contiguous, 48 MB total
    bf16_t* Xb  = (bf16_t*)d_ws;                       // 4M
    bf16_t* Wqb = Xb  + (size_t)MROWS * D_MODEL;       // 3M (Wq|Wk|Wv)
    bf16_t* Wob = Wqb + (size_t)3 * D_MODEL * D_MODEL; // 1M
    bf16_t* Qw  = Wob + (size_t)D_MODEL * D_MODEL;     // 4M  [B,H,T,D], pre-scaled
    bf16_t* Kw  = Qw  + (size_t)MROWS * D_MODEL;       // 4M  [B,H,T,D]
    bf16_t* Vt  = Kw  + (size_t)MROWS * D_MODEL;       // 4M  [B,H,D,T]
    bf16_t* Ow  = Vt  + (size_t)MROWS * D_MODEL;       // 4M  V-raw, then attn out [B,T,H,D]

    // 1) convert all inputs to bf16
    cvt_all_kernel<<<(MROWS*D_MODEL + 4*D_MODEL*D_MODEL) / 4 / 256, 256, 0, stream>>>(
        x, Wq, Wk, Wv, Wo, Xb);

    // 2) fused QKV projection (V-raw lands in the Ow slot, coalesced)
    dim3 gqkv(3 * D_MODEL / 128, MROWS / 128);
    gemm_bt<0,128><<<gqkv, 256, 0, stream>>>(Xb, Wqb, Qw, MROWS, 3 * D_MODEL, D_MODEL);

    // 3) V transpose -> [B,H,D,T]
    dim3 gt(TT / 64, BB * HEADS);
    transpose_v<<<gt, 256, 0, stream>>>(Ow, Vt);

    // 4) flash attention (overwrites Ow with attention output); 1024 blocks
    attn_kernel<<<dim3(1024), 256, 0, stream>>>(Qw, Kw, Vt, Ow);

    // 5) output projection -> fp32 d_out (64-col tiles: 512 blocks = 2/CU)
    dim3 go(D_MODEL / 64, MROWS / 128);
    gemm_bt<2,64><<<go, 256, 0, stream>>>(Ow, Wob, out, MROWS, D_MODEL, D_MODEL);
}

// Round 11
// 165.463 us; speedup vs baseline: 1.3716x; 1.0441x over previous
//
#include <hip/hip_runtime.h>
#include <hip/hip_bf16.h>

// ---- types ----
typedef __bf16 bf16_t;
typedef __bf16 bf16x2 __attribute__((ext_vector_type(2)));
typedef __bf16 bf16x4 __attribute__((ext_vector_type(4)));
typedef __bf16 bf16x8 __attribute__((ext_vector_type(8)));
typedef float  f32x4  __attribute__((ext_vector_type(4)));
typedef int    i32x2  __attribute__((ext_vector_type(2)));

#define D_MODEL 1024
#define HEADS   16
#define HD      64
#define BB      2
#define TT      2048
#define MROWS   (BB*TT)   // 4096

#define GLDS16(g, l) __builtin_amdgcn_global_load_lds( \
    (const __attribute__((address_space(1))) void*)(g), \
    (__attribute__((address_space(3))) void*)(l), 16, 0, 0)

static __device__ __forceinline__ int pack_bf16(float a, float b) {
    bf16x2 t; t[0] = (bf16_t)a; t[1] = (bf16_t)b;
    return __builtin_bit_cast(int, t);
}

// ---------------- fused fp32 -> bf16 convert ----------------
__global__ __launch_bounds__(256) void cvt_all_kernel(const float* __restrict__ x,
                                                      const float* __restrict__ wq,
                                                      const float* __restrict__ wk,
                                                      const float* __restrict__ wv,
                                                      const float* __restrict__ wo,
                                                      bf16_t* __restrict__ dst) {
    const int i = blockIdx.x * 256 + threadIdx.x;   // vec4 index, total 2097152
    const float* src;
    int s;
    if (i < 1048576) { src = x; s = i; }
    else {
        int j = i - 1048576;
        int w = j >> 18;          // 262144 vec4 per weight
        s = j & 262143;
        src = (w == 0) ? wq : (w == 1) ? wk : (w == 2) ? wv : wo;
    }
    float4 v = reinterpret_cast<const float4*>(src)[s];
    bf16x4 o;
    o[0] = (bf16_t)v.x; o[1] = (bf16_t)v.y; o[2] = (bf16_t)v.z; o[3] = (bf16_t)v.w;
    reinterpret_cast<bf16x4*>(dst)[i] = o;
}

// ---------------- bf16 GEMM: C[M,N] = A[M,K] * B[N,K]^T ----------------
// R12 (verified): BK=64 + XOR swizzle (LDS rows 128B = 8 chunks of 16B;
// staging pre-swizzles the GLOBAL source chunk (chunk ^ (row&7), linear LDS
// dest — GLDS-legal) and reads use ((h*4+quad) ^ (row&7))). Old BK=32 layout
// had row-stride 64B -> 8-way ds_read_b128 conflicts (3.1M cycles).
// R13: MODE0 epilogue writes V DIRECTLY TRANSPOSED into the Vt slot
// ([B,H,D,T]) as bf16x4 over r (acc[..][r] holds 4 consecutive t for fixed d)
// — eliminates the transpose_v kernel and V's round-trip through Ow.
// Scattered 8B stores (d-stride 4KB) are absorbed by L2; Vt lines end fully
// dirty so HBM writeback stays 8MB.
// BN = 128 or 64 (N-tile). M-tile fixed 128.
// MODE 0: fused QKV scatter (N=3072): Q at Cout+0 ([B,H,T,D], pre-scaled by
//         0.125*log2e), K at +4M ([B,H,T,D]), V at +8M ([B,H,D,T] direct).
// MODE 2: fp32 row-major [M,N] (final output)
template<int MODE, int BN>
__global__ __launch_bounds__(256, 3) void gemm_bt(const bf16_t* __restrict__ A,
                                                  const bf16_t* __restrict__ Bw,
                                                  void* __restrict__ Cout,
                                                  int M, int N, int K) {
    constexpr int NI = BN / 32;     // n-tiles of 16 per wave
    __shared__ __align__(16) bf16_t As[128*64];
    __shared__ __align__(16) bf16_t Bs[BN*64];
    const int tid   = threadIdx.x;
    const int lane  = tid & 63;
    const int wave  = tid >> 6;
    const int col16 = lane & 15;
    const int quad  = lane >> 4;
    const int wrow  = (wave & 1) * 64;
    const int wcol  = (wave >> 1) * (BN / 2);
    const int bm    = blockIdx.y * 128;
    const int bn    = blockIdx.x * BN;
    const int x7    = col16 & 7;    // row&7 for all fragment rows (wrow,mi*16 = 0 mod 8)

    // staging: shot = 256 threads x 16B = 4KB = 32 rows x 64 cols (bf16).
    // thread -> row lr = tid>>3 (0..31), LDS chunk slot tid&7; global chunk
    // fetched = (tid&7) ^ (lr&7)  => LDS slot c of row r holds global chunk
    // c ^ (r&7); reads invert with the same XOR.
    const int lr = tid >> 3;
    const int lc = ((tid & 7) ^ (lr & 7)) * 8;

    const bf16_t* agp = &A [(size_t)(bm + lr)*K + lc];
    const bf16_t* bgp = &Bw[(size_t)(bn + lr)*K + lc];

    f32x4 acc[4][NI];
#pragma unroll
    for (int i = 0; i < 4; i++)
#pragma unroll
        for (int j = 0; j < NI; j++) acc[i][j] = (f32x4){0.f, 0.f, 0.f, 0.f};

    for (int k0 = 0; k0 < K; k0 += 64) {
#pragma unroll
        for (int s = 0; s < 4; s++)             // A: 128 rows = 4 shots
            GLDS16(agp + k0 + (size_t)s*32*K, &As[s*2048 + wave*512]);
#pragma unroll
        for (int s = 0; s < BN/32; s++)         // B: BN rows
            GLDS16(bgp + k0 + (size_t)s*32*K, &Bs[s*2048 + wave*512]);
        __syncthreads();

        bf16x8 af[4][2], bfr[NI][2];
#pragma unroll
        for (int mi = 0; mi < 4; mi++)
#pragma unroll
            for (int h = 0; h < 2; h++)
                af[mi][h] = *reinterpret_cast<const bf16x8*>(
                    &As[(wrow + mi*16 + col16)*64 + ((h*4 + quad) ^ x7)*8]);
#pragma unroll
        for (int ni = 0; ni < NI; ni++)
#pragma unroll
            for (int h = 0; h < 2; h++)
                bfr[ni][h] = *reinterpret_cast<const bf16x8*>(
                    &Bs[(wcol + ni*16 + col16)*64 + ((h*4 + quad) ^ x7)*8]);
#pragma unroll
        for (int mi = 0; mi < 4; mi++)
#pragma unroll
            for (int ni = 0; ni < NI; ni++) {
                acc[mi][ni] = __builtin_amdgcn_mfma_f32_16x16x32_bf16(af[mi][0], bfr[ni][0], acc[mi][ni], 0, 0, 0);
                acc[mi][ni] = __builtin_amdgcn_mfma_f32_16x16x32_bf16(af[mi][1], bfr[ni][1], acc[mi][ni], 0, 0, 0);
            }
        __syncthreads();
    }

    // epilogue: C/D layout col=lane&15, row=quad*4+reg
#pragma unroll
    for (int mi = 0; mi < 4; mi++) {
        const int gm = bm + wrow + mi*16 + quad*4;   // r=0 row; r-run stays in one b
        const int t  = gm & (TT - 1);
        const int b  = gm >> 11;          // TT = 2048
#pragma unroll
        for (int ni = 0; ni < NI; ni++) {
            const int gn = bn + wcol + ni*16 + col16;
            if (MODE == 2) {
#pragma unroll
                for (int r = 0; r < 4; r++)
                    reinterpret_cast<float*>(Cout)[(size_t)(gm + r) * N + gn] = acc[mi][ni][r];
            } else {
                const int which = gn >> 10;       // 0=Q 1=K 2=V
                const int n = gn & 1023;
                const int h = n >> 6, d = n & 63;
                if (which == 2) {
                    // direct V^T: Vt[b,h,d,t..t+3] (8B store; acc r-run = t-run)
                    bf16x4 o4;
#pragma unroll
                    for (int r = 0; r < 4; r++) o4[r] = (bf16_t)acc[mi][ni][r];
                    bf16_t* vt = reinterpret_cast<bf16_t*>(Cout) + (size_t)2 * MROWS * D_MODEL;
                    *reinterpret_cast<bf16x4*>(&vt[(((size_t)(b*HEADS + h))*HD + d)*TT + t]) = o4;
                } else {
                    bf16_t* base = reinterpret_cast<bf16_t*>(Cout) + (size_t)which * MROWS * D_MODEL;
#pragma unroll
                    for (int r = 0; r < 4; r++) {
                        float v = acc[mi][ni][r];
                        if (which == 0) v *= 0.18033688f; // 0.125 * log2(e), fp32 pre-rounding
                        base[(((size_t)(b*HEADS + h))*TT + (t + r))*HD + d] = (bf16_t)v;
                    }
                }
            }
        }
    }
}

// ---------------- flash attention: 4 waves/block, 64 q-rows, 64-key tiles ----
// R11 (unchanged, verified): R8 structure + s_setprio around pure-MFMA
// clusters (T5 attn-regime). Waves = (kw key-half, qw query-half): 32q x 32k
// sub-tile per wave; partials over disjoint key halves exactly additive
// (no-max softmax) -> one LDS merge. PV B-frag redistribution via
// permlane{32,16}_swap builtins. Balanced packing {31-g, g, 15-g, 16+g}:
// CU-set of 4 sums to 66 rounds.
// S^T formulation: S^T = K.Q^T; Q pre-scaled by 0.125*log2e. Vt: [B,H,D,T].
__global__ __launch_bounds__(256, 4) void attn_kernel(const bf16_t* __restrict__ Q,
                                                      const bf16_t* __restrict__ Kk,
                                                      const bf16_t* __restrict__ Vt,
                                                      bf16_t* __restrict__ O) {
    __shared__ __align__(16) bf16_t Ks[2][64*64];   // [key][d-chunks], XOR-swizzled
    __shared__ __align__(16) bf16_t Vs[2][64*64];   // [d][key-chunks], XOR-swizzled

    const int tid   = threadIdx.x;
    const int lane  = tid & 63;
    const int wave  = tid >> 6;
    const int col16 = lane & 15;
    const int quad  = lane >> 4;
    const int kw    = wave & 1;    // key-half this wave owns (keys kw*32..kw*32+31)
    const int qw    = wave >> 1;   // query-half this wave owns (rows qb+qw*32..+31)

    const int bx = blockIdx.x;
    const int r_ = bx >> 8, s_ = bx & 255;
    const int bh = s_ & 31;
    const int g  = s_ >> 5;
    // balanced partition: {31-g, g, 15-g, 16+g} -> uniform 66 rounds per CU-set
    const int qt = (r_ == 0) ? (31 - g)
                 : (r_ == 1) ? g
                 : (r_ == 2) ? (15 - g)
                             : (16 + g);
    const int qb    = qt * 64;
    const int qbase = qb + qw * 32;
    const int nkt   = qt + 1;

    const bf16_t* Qb = Q  + (size_t)bh * TT * HD;
    const bf16_t* Kb = Kk + (size_t)bh * TT * HD;
    const bf16_t* Vb = Vt + (size_t)bh * HD * TT;

    // Q fragments (B-operand layout B[k=d][n=q]) for both 16-row query groups
    bf16x8 qf[2][2];
#pragma unroll
    for (int qg = 0; qg < 2; qg++)
#pragma unroll
        for (int h = 0; h < 2; h++)
            qf[qg][h] = *reinterpret_cast<const bf16x8*>(
                &Qb[(size_t)(qbase + qg*16 + col16)*HD + h*32 + quad*8]);

    // staging geometry: each shot = 256 threads x 16B = 4KB = 32 rows x 64 cols.
    // LDS[row*64 + ch*8 + i] = src[row][(ch ^ (row&7))*8 + i]  (XOR swizzle).
    const int srow = (tid >> 3) & 31;
    const int sg   = ((lane & 7) ^ (srow & 7)) * 8;

    auto stage = [&](int kt, int buf) {
        const int s0 = kt * 64;
        GLDS16(&Kb[(size_t)(s0 + srow)*HD + sg],        &Ks[buf][wave*512]);
        GLDS16(&Kb[(size_t)(s0 + srow + 32)*HD + sg],   &Ks[buf][2048 + wave*512]);
        GLDS16(&Vb[(size_t)srow*TT + s0 + sg],          &Vs[buf][wave*512]);
        GLDS16(&Vb[(size_t)(srow + 32)*TT + s0 + sg],   &Vs[buf][2048 + wave*512]);
    };

    // out^T partial over this wave's key half:
    // acc[c][qg][r] = O^T[d = c*16+quad*4+r][q = qg*16+col16]
    f32x4 acc[4][2];
#pragma unroll
    for (int i = 0; i < 4; i++)
#pragma unroll
        for (int j = 0; j < 2; j++) acc[i][j] = (f32x4){0.f,0.f,0.f,0.f};
    float lsum[2] = {0.f, 0.f};     // partial softmax denoms (this key half)

    const int x7 = col16 & 7;

    stage(0, 0);
    __syncthreads();

    for (int kt = 0; kt < nkt; kt++) {
        const int buf = kt & 1;
        if (kt + 1 < nkt) stage(kt + 1, buf ^ 1);   // async prefetch, drained by end barrier
        const int s0 = kt * 64;
        const bool diag = (kt == nkt - 1);

        // ---- S^T = K Q^T on this wave's 32 keys x 32 queries ----
        bf16x8 kf0[2], kf1[2];
#pragma unroll
        for (int c = 0; c < 2; c++) {
            // K A-frag: A[m=key][k=d]: lane holds K[s0+kw*32+c*16+col16][d-chunk]
            kf0[c] = *reinterpret_cast<const bf16x8*>(
                &Ks[buf][(kw*32 + c*16 + col16)*64 + ((0*4 + quad) ^ x7)*8]);
            kf1[c] = *reinterpret_cast<const bf16x8*>(
                &Ks[buf][(kw*32 + c*16 + col16)*64 + ((1*4 + quad) ^ x7)*8]);
        }

        int pk[2][2][2];   // pk[c][qg][x]: keys kw*32+c*16+quad*4+{2x,2x+1}, query qg*16+col16
#pragma unroll
        for (int c = 0; c < 2; c++) {
#pragma unroll
            for (int qg = 0; qg < 2; qg++) {
                __builtin_amdgcn_s_setprio(1);
                f32x4 sv = __builtin_amdgcn_mfma_f32_16x16x32_bf16(kf0[c], qf[qg][0], (f32x4){0.f,0.f,0.f,0.f}, 0, 0, 0);
                sv       = __builtin_amdgcn_mfma_f32_16x16x32_bf16(kf1[c], qf[qg][1], sv, 0, 0, 0);
                __builtin_amdgcn_s_setprio(0);

                float pr[4];
#pragma unroll
                for (int r = 0; r < 4; r++) pr[r] = exp2f(sv[r]);   // scale baked into Q
                if (diag) {   // causal mask, block-uniform branch
#pragma unroll
                    for (int r = 0; r < 4; r++)
                        if (s0 + kw*32 + c*16 + quad*4 + r > qbase + qg*16 + col16) pr[r] = 0.f;
                }
                lsum[qg] += (pr[0] + pr[1]) + (pr[2] + pr[3]);
                pk[c][qg][0] = pack_bf16(pr[0], pr[1]);
                pk[c][qg][1] = pack_bf16(pr[2], pr[3]);
            }
        }

        // ---- PV: out^T += V^T P^T over this wave's 32-key chunk ----
        bf16x8 pf[2];
#pragma unroll
        for (int qg = 0; qg < 2; qg++) {
#if __has_builtin(__builtin_amdgcn_permlane32_swap)
            i32x2 u0 = __builtin_amdgcn_permlane32_swap(pk[0][qg][0], pk[1][qg][0], false, false);
            i32x2 v0 = __builtin_amdgcn_permlane16_swap(u0[0], u0[1], false, false);
            i32x2 u1 = __builtin_amdgcn_permlane32_swap(pk[0][qg][1], pk[1][qg][1], false, false);
            i32x2 v1 = __builtin_amdgcn_permlane16_swap(u1[0], u1[1], false, false);
            int4 bi = { v0[0], v1[0], v0[1], v1[1] };   // slots 0,1,2,3
#else
            const int a1 = ((quad & 1) * 32 + col16) * 4;
            const int a2 = a1 + 64;
            const bool hi = quad >= 2;
            int b0l = __builtin_amdgcn_ds_bpermute(a1, pk[0][qg][0]);
            int b0h = __builtin_amdgcn_ds_bpermute(a1, pk[1][qg][0]);
            int b1l = __builtin_amdgcn_ds_bpermute(a1, pk[0][qg][1]);
            int b1h = __builtin_amdgcn_ds_bpermute(a1, pk[1][qg][1]);
            int b2l = __builtin_amdgcn_ds_bpermute(a2, pk[0][qg][0]);
            int b2h = __builtin_amdgcn_ds_bpermute(a2, pk[1][qg][0]);
            int b3l = __builtin_amdgcn_ds_bpermute(a2, pk[0][qg][1]);
            int b3h = __builtin_amdgcn_ds_bpermute(a2, pk[1][qg][1]);
            int4 bi = { hi ? b0h : b0l, hi ? b1h : b1l, hi ? b2h : b2l, hi ? b3h : b3l };
#endif
            pf[qg] = __builtin_bit_cast(bf16x8, bi);
        }
        __builtin_amdgcn_s_setprio(1);
#pragma unroll
        for (int c = 0; c < 4; c++) {
            // V^T A-frag: A[m=d][k=key]: lane holds V^T[c*16+col16][s0+kw*32+quad*8+j]
            bf16x8 vf = *reinterpret_cast<const bf16x8*>(
                &Vs[buf][(c*16 + col16)*64 + ((kw*4 + quad) ^ x7)*8]);
            acc[c][0] = __builtin_amdgcn_mfma_f32_16x16x32_bf16(vf, pf[0], acc[c][0], 0, 0, 0);
            acc[c][1] = __builtin_amdgcn_mfma_f32_16x16x32_bf16(vf, pf[1], acc[c][1], 0, 0, 0);
        }
        __builtin_amdgcn_s_setprio(0);
        __syncthreads();   // drains prefetch (vmcnt0) + protects LDS buffers
    }

    // partial denoms: sum across quads (same query col16) within the wave
#pragma unroll
    for (int qg = 0; qg < 2; qg++) {
        lsum[qg] += __shfl_xor(lsum[qg], 16);
        lsum[qg] += __shfl_xor(lsum[qg], 32);
    }

    // ---- cross-kw merge (partials are additive: no-max softmax) ----
    // kw=1 waves park their partials in LDS (reusing the K/V buffers, which
    // the final loop barrier has released); qw selects the buffer so the two
    // kw=1 waves never collide. Layout: M[32 q][68 d] f32 (pad 68 vs 64).
    float* Mq = qw ? reinterpret_cast<float*>(&Vs[0][0])
                   : reinterpret_cast<float*>(&Ks[0][0]);
    float* LS = reinterpret_cast<float*>(&Vs[0][0]) + 32*68;   // 64 denom slots

    if (kw == 1) {
#pragma unroll
        for (int c = 0; c < 4; c++)
#pragma unroll
            for (int qg = 0; qg < 2; qg++)
                *reinterpret_cast<f32x4*>(&Mq[(qg*16 + col16)*68 + c*16 + quad*4]) = acc[c][qg];
        if (lane < 16) {
            LS[qw*32 + lane]      = lsum[0];
            LS[qw*32 + 16 + lane] = lsum[1];
        }
    }
    __syncthreads();

    if (kw == 0) {
        const int b_ = bh >> 4, h = bh & 15;
#pragma unroll
        for (int qg = 0; qg < 2; qg++) {
            const float l   = lsum[qg] + LS[qw*32 + qg*16 + col16];
            const float inv = 1.0f / l;
            const int t = qbase + qg*16 + col16;
            bf16_t* Ob = &O[(((size_t)(b_*TT + t))*HEADS + h)*HD + quad*4];
#pragma unroll
            for (int c = 0; c < 4; c++) {
                f32x4 m = *reinterpret_cast<const f32x4*>(&Mq[(qg*16 + col16)*68 + c*16 + quad*4]);
                bf16x4 o4;
#pragma unroll
                for (int r = 0; r < 4; r++) o4[r] = (bf16_t)((acc[c][qg][r] + m[r]) * inv);
                *reinterpret_cast<bf16x4*>(&Ob[c*16]) = o4;
            }
        }
    }
}

// ---------------- launch ----------------
extern "C" void kernel_launch(void* const* d_in, const int* in_sizes, int n_in,
                              void* d_out, int out_size, void* d_ws, size_t ws_size,
                              hipStream_t stream) {
    const float* x  = (const float*)d_in[0];
    const float* Wq = (const float*)d_in[1];
    const float* Wk = (const float*)d_in[2];
    const float* Wv = (const float*)d_in[3];
    const float* Wo = (const float*)d_in[4];
    float* out = (float*)d_out;

    // workspace layout (bf16 elements), contiguous, 48 MB total
    bf16_t* Xb  = (bf16_t*)d_ws;                       // 4M
    bf16_t* Wqb = Xb  + (size_t)MROWS * D_MODEL;       // 3M (Wq|Wk|Wv)
    bf16_t* Wob = Wqb + (size_t)3 * D_MODEL * D_MODEL; // 1M
    bf16_t* Qw  = Wob + (size_t)D_MODEL * D_MODEL;     // 4M  [B,H,T,D], pre-scaled
    bf16_t* Kw  = Qw  + (size_t)MROWS * D_MODEL;       // 4M  [B,H,T,D]
    bf16_t* Vt  = Kw  + (size_t)MROWS * D_MODEL;       // 4M  [B,H,D,T] (written directly by gemm0)
    bf16_t* Ow  = Vt  + (size_t)MROWS * D_MODEL;       // 4M  attn out [B,T,H,D]

    // 1) convert all inputs to bf16
    cvt_all_kernel<<<(MROWS*D_MODEL + 4*D_MODEL*D_MODEL) / 4 / 256, 256, 0, stream>>>(
        x, Wq, Wk, Wv, Wo, Xb);

    // 2) fused QKV projection (V written directly transposed into Vt)
    dim3 gqkv(3 * D_MODEL / 128, MROWS / 128);
    gemm_bt<0,128><<<gqkv, 256, 0, stream>>>(Xb, Wqb, Qw, MROWS, 3 * D_MODEL, D_MODEL);

    // 3) flash attention (writes Ow); 1024 blocks
    attn_kernel<<<dim3(1024), 256, 0, stream>>>(Qw, Kw, Vt, Ow);

    // 4) output projection -> fp32 d_out (64-col tiles: 512 blocks = 2/CU)
    dim3 go(D_MODEL / 64, MROWS / 128);
    gemm_bt<2,64><<<go, 256, 0, stream>>>(Ow, Wob, out, MROWS, D_MODEL, D_MODEL);
}